// Round 1
// baseline (1916.523 us; speedup 1.0000x reference)
//
#include <hip/hip_runtime.h>
#include <hip/hip_bf16.h>
#include <cstdint>
#include <cmath>

#define NROWS 4096
#define DIM   2048
#define CNUM  128
#define MARGIN_F 0.3f

#define BM 64
#define BN 64
#define BK 16
#define SLICES 8
#define COLS_PER_SLICE (NROWS / SLICES)   // 512
#define TOPK 12
#define MAXM 256   // max class size (expected ~32, hard cap)

__device__ __forceinline__ uint32_t rnd_u32(uint32_t row, uint32_t k) {
    uint64_t x = ((uint64_t)row << 32) ^ (0x9E3779B97F4A7C15ULL * (uint64_t)(k + 1u));
    x ^= x >> 33; x *= 0xff51afd7ed558ccdULL;
    x ^= x >> 33; x *= 0xc4ceb9fe1a85ec53ULL;
    x ^= x >> 33;
    return (uint32_t)x;
}

// ---------- kernel 1a: row sum of squares (one wave per row) ----------
__global__ void rowsq_kernel(const float* __restrict__ X, float* __restrict__ sq) {
    int wave = (blockIdx.x * blockDim.x + threadIdx.x) >> 6;
    int lane = threadIdx.x & 63;
    if (wave >= NROWS) return;
    const float4* xp = (const float4*)(X + (size_t)wave * DIM);
    float s = 0.f;
    for (int k = lane; k < DIM / 4; k += 64) {
        float4 v = xp[k];
        s += v.x * v.x + v.y * v.y + v.z * v.z + v.w * v.w;
    }
    for (int off = 32; off; off >>= 1) s += __shfl_xor(s, off, 64);
    if (lane == 0) sq[wave] = s;
}

// ---------- kernel 1b: pred_cls = argmax over C=128 (one wave per row) ----------
__global__ void predcls_kernel(const float* __restrict__ P, int* __restrict__ cls) {
    int row = (blockIdx.x * blockDim.x + threadIdx.x) >> 6;
    int lane = threadIdx.x & 63;
    if (row >= NROWS) return;
    const float* p = P + (size_t)row * CNUM;
    float v0 = p[lane]; int i0 = lane;
    float v1 = p[lane + 64];
    if (v1 > v0) { v0 = v1; i0 = lane + 64; }   // first-max semantics: strict >
    for (int off = 1; off < 64; off <<= 1) {
        float ov = __shfl_xor(v0, off, 64);
        int   oi = __shfl_xor(i0, off, 64);
        if (ov > v0 || (ov == v0 && oi < i0)) { v0 = ov; i0 = oi; }
    }
    if (lane == 0) cls[row] = i0;
}

// ---------- kernel 2: per-class member lists (ascending index order) ----------
__global__ void classlist_kernel(const int* __restrict__ tgt,
                                 int* __restrict__ cnt, int* __restrict__ members) {
    int c = blockIdx.x * blockDim.x + threadIdx.x;
    if (c >= CNUM) return;
    int k = 0;
    for (int i = 0; i < NROWS; i++) {
        if (tgt[i] == c) {
            if (k < MAXM) members[c * MAXM + k] = i;
            k++;
        }
    }
    cnt[c] = (k < MAXM) ? k : MAXM;
}

// ---------- kernel 3: fused fp32 GEMM + per-row top-12 negative mining ----------
// grid: (NROWS/BM, SLICES); block: 256 threads
__launch_bounds__(256)
__global__ void dist_topk_kernel(const float* __restrict__ X, const float* __restrict__ sq,
                                 const int* __restrict__ tgt,
                                 float* __restrict__ part_v, int* __restrict__ part_i) {
    __shared__ float As[BK][BM];
    __shared__ float Bs[BK][BN];
    __shared__ float Cs[BM][BN + 1];
    __shared__ float sqA[BM], sqB[BN];
    __shared__ int   tgA[BM], tgB[BN];

    int rowBase = blockIdx.x * BM;
    int slice = blockIdx.y;
    int tid = threadIdx.x;
    int tx = tid & 15, ty = tid >> 4;

    if (tid < BM) { sqA[tid] = sq[rowBase + tid]; tgA[tid] = tgt[rowBase + tid]; }

    // register-resident top-12 list (only threads 0..63 meaningfully use it)
    float lv[TOPK]; int li[TOPK];
#pragma unroll
    for (int k = 0; k < TOPK; k++) { lv[k] = INFINITY; li[k] = -1; }

    for (int jt = 0; jt < COLS_PER_SLICE / BN; jt++) {
        int colBase = slice * COLS_PER_SLICE + jt * BN;
        __syncthreads();   // previous iter's scan of Cs must be done
        if (tid < BN) { sqB[tid] = sq[colBase + tid]; tgB[tid] = tgt[colBase + tid]; }

        float acc[4][4] = {};
        for (int kb = 0; kb < DIM; kb += BK) {
            int r  = tid >> 2;
            int kk = (tid & 3) * 4;
            float4 va = *(const float4*)(X + (size_t)(rowBase + r) * DIM + kb + kk);
            As[kk + 0][r] = va.x; As[kk + 1][r] = va.y; As[kk + 2][r] = va.z; As[kk + 3][r] = va.w;
            float4 vb = *(const float4*)(X + (size_t)(colBase + r) * DIM + kb + kk);
            Bs[kk + 0][r] = vb.x; Bs[kk + 1][r] = vb.y; Bs[kk + 2][r] = vb.z; Bs[kk + 3][r] = vb.w;
            __syncthreads();
#pragma unroll
            for (int k = 0; k < BK; k++) {
                float a[4], b[4];
                *(float4*)a = *(const float4*)&As[k][ty * 4];
                *(float4*)b = *(const float4*)&Bs[k][tx * 4];
#pragma unroll
                for (int i2 = 0; i2 < 4; i2++)
#pragma unroll
                    for (int j2 = 0; j2 < 4; j2++)
                        acc[i2][j2] += a[i2] * b[j2];
            }
            __syncthreads();
        }
        // epilogue: squared distances with positive-mask into Cs
#pragma unroll
        for (int i2 = 0; i2 < 4; i2++) {
            int r = ty * 4 + i2;
#pragma unroll
            for (int j2 = 0; j2 < 4; j2++) {
                int c = tx * 4 + j2;
                float d2 = sqA[r] + sqB[c] - 2.f * acc[i2][j2];
                if (tgA[r] == tgB[c]) d2 = INFINITY;   // positives (incl. diagonal) excluded
                Cs[r][c] = d2;
            }
        }
        __syncthreads();
        // per-row top-12 update (threads 0..63, one row each)
        if (tid < BM) {
            int r = tid;
            for (int c = 0; c < BN; c++) {
                float v = Cs[r][c];
                if (v < lv[TOPK - 1]) {
                    float nv = v; int ni = colBase + c;
#pragma unroll
                    for (int p = 0; p < TOPK; p++) {
                        if (nv < lv[p]) {
                            float tv = lv[p]; int ti = li[p];
                            lv[p] = nv; li[p] = ni;
                            nv = tv; ni = ti;
                        }
                    }
                }
            }
        }
    }
    if (tid < BM) {
        int r = tid;
#pragma unroll
        for (int k = 0; k < TOPK; k++) {
            size_t o = ((size_t)(rowBase + r) * SLICES + slice) * TOPK + k;
            part_v[o] = lv[k];
            part_i[o] = li[k];
        }
    }
}

// ---------- kernel 4: merge 8 partial top-12 lists per row ----------
__global__ void topk_merge_kernel(const float* __restrict__ part_v, const int* __restrict__ part_i,
                                  float* __restrict__ top_v, int* __restrict__ top_i) {
    int row = blockIdx.x * blockDim.x + threadIdx.x;
    if (row >= NROWS) return;
    float lv[TOPK]; int li[TOPK];
#pragma unroll
    for (int k = 0; k < TOPK; k++) { lv[k] = INFINITY; li[k] = -1; }
    for (int s = 0; s < SLICES; s++) {
        for (int k = 0; k < TOPK; k++) {
            size_t o = ((size_t)row * SLICES + s) * TOPK + k;
            float v = part_v[o];
            if (!(v < lv[TOPK - 1])) break;   // slice lists ascending
            int idx = part_i[o];
            float nv = v; int ni = idx;
#pragma unroll
            for (int p = 0; p < TOPK; p++) {
                if (nv < lv[p]) {
                    float tv = lv[p]; int ti = li[p];
                    lv[p] = nv; li[p] = ni;
                    nv = tv; ni = ti;
                }
            }
        }
    }
#pragma unroll
    for (int k = 0; k < TOPK; k++) {
        top_v[(size_t)row * TOPK + k] = lv[k];
        top_i[(size_t)row * TOPK + k] = li[k];
    }
}

// ---------- kernel 5: per-row triplet logic (one wave per row) ----------
__global__ void rowlogic_kernel(const float* __restrict__ X, const float* __restrict__ sq,
                                const float* __restrict__ prob, const float* __restrict__ thr_p,
                                const int* __restrict__ tgt, const int* __restrict__ pred_cls,
                                const int* __restrict__ class_cnt, const int* __restrict__ class_mem,
                                const float* __restrict__ top_v, const int* __restrict__ top_i,
                                float* __restrict__ row_loss, int* __restrict__ row_corr) {
    int i = (blockIdx.x * blockDim.x + threadIdx.x) >> 6;
    int lane = threadIdx.x & 63;
    if (i >= NROWS) return;
    float thr = *thr_p;

    // control flow is wave-uniform; compute redundantly on all lanes (broadcast loads)
    int c = tgt[i];
    int cc = class_cnt[c];
    const int* mem = class_mem + c * MAXM;

    int pos_i = 0;
    for (int k = 0; k < cc; k++) { if (mem[k] == i) { pos_i = k; break; } }

    // rp: uniform over class members excluding i
    int rp = 0;
    if (cc > 1) {
        uint32_t r = rnd_u32((uint32_t)i, 0x9111u) % (uint32_t)(cc - 1);
        if ((int)r >= pos_i) r++;
        rp = mem[r];
    }

    int hn = top_i[(size_t)i * TOPK + 0];
    float an0 = sqrtf(fmaxf(top_v[(size_t)i * TOPK + 0], 1e-12f));
    bool p_neg = prob[hn] >= thr;
    bool is_FN = (pred_cls[hn] == c);

    // hn_new: first confident among ranks 1..11 else rank 11
    int sel = 11;
    for (int k = 1; k <= 11; k++) {
        int cd = top_i[(size_t)i * TOPK + k];
        if (prob[cd] >= thr) { sel = k; break; }
    }
    float anB = sqrtf(fmaxf(top_v[(size_t)i * TOPK + sel], 1e-12f));

    // 6 draws uniform over class (incl. i); rp_new = first valid else last draw
    int first_valid = -1, last_draw = 0;
    for (int k = 0; k < 6; k++) {
        uint32_t r = rnd_u32((uint32_t)i, 0xD000u + (uint32_t)k) % (uint32_t)(cc > 0 ? cc : 1);
        int dk = mem[r];
        last_draw = dk;
        if (first_valid < 0 && dk != i && prob[dk] >= thr) first_valid = dk;
    }
    int rp_new = (first_valid >= 0) ? first_valid : last_draw;
    bool p_pos = prob[rp] >= thr;

    // exact dots for rp and rp_new (wave-cooperative)
    const float4* xi = (const float4*)(X + (size_t)i * DIM);
    const float4* xr = (const float4*)(X + (size_t)rp * DIM);
    const float4* xn = (const float4*)(X + (size_t)rp_new * DIM);
    float s1 = 0.f, s2 = 0.f;
    for (int k = lane; k < DIM / 4; k += 64) {
        float4 a = xi[k], b = xr[k], d = xn[k];
        s1 += a.x * b.x + a.y * b.y + a.z * b.z + a.w * b.w;
        s2 += a.x * d.x + a.y * d.y + a.z * d.z + a.w * d.w;
    }
    for (int off = 32; off; off >>= 1) {
        s1 += __shfl_xor(s1, off, 64);
        s2 += __shfl_xor(s2, off, 64);
    }
    if (lane == 0) {
        float ap0 = sqrtf(fmaxf(sq[i] + sq[rp]     - 2.f * s1, 1e-12f));
        float apC = sqrtf(fmaxf(sq[i] + sq[rp_new] - 2.f * s2, 1e-12f));
        float apB = (ap0 + an0) * 0.5f;
        float anC = (ap0 + an0) * 0.5f;
        bool useB = p_pos && !p_neg && is_FN;
        bool useC = (!p_pos && p_neg) || (!p_pos && !p_neg && !is_FN);
        bool inverse = !p_pos && !p_neg && is_FN;
        float ap = useB ? apB : (useC ? apC : ap0);
        float an = useB ? anB : (useC ? anC : an0);
        float pl = inverse ? fmaxf(an - ap + MARGIN_F, 0.f)
                           : fmaxf(ap - an + MARGIN_F, 0.f);
        bool conf = prob[i] >= thr;
        row_loss[i] = conf ? pl : 0.f;
        row_corr[i] = (conf && (an >= ap)) ? 1 : 0;
    }
}

// ---------- kernel 6: final reduction ----------
__global__ void reduce_kernel(const float* __restrict__ row_loss, const int* __restrict__ row_corr,
                              const float* __restrict__ prob, const float* __restrict__ thr_p,
                              float* __restrict__ out) {
    __shared__ float sl[256];
    __shared__ int   sc[256];
    __shared__ int   sn[256];
    float thr = *thr_p;
    int tid = threadIdx.x;
    float l = 0.f; int corr = 0, cnt = 0;
    for (int i = tid; i < NROWS; i += 256) {
        l += row_loss[i];
        corr += row_corr[i];
        cnt += (prob[i] >= thr) ? 1 : 0;
    }
    sl[tid] = l; sc[tid] = corr; sn[tid] = cnt;
    __syncthreads();
    for (int off = 128; off; off >>= 1) {
        if (tid < off) {
            sl[tid] += sl[tid + off];
            sc[tid] += sc[tid + off];
            sn[tid] += sn[tid + off];
        }
        __syncthreads();
    }
    if (tid == 0) {
        int cn = sn[0];
        float loss = (cn > 0) ? (sl[0] / (float)(cn > 1 ? cn : 1)) : 0.f;
        out[0] = loss;
        out[1] = (float)sc[0];
        out[2] = (float)cn;
    }
}

extern "C" void kernel_launch(void* const* d_in, const int* in_sizes, int n_in,
                              void* d_out, int out_size, void* d_ws, size_t ws_size,
                              hipStream_t stream) {
    const float* X    = (const float*)d_in[0];   // (N, D)
    const float* P    = (const float*)d_in[1];   // (N, C)
    const int*   tgt  = (const int*)d_in[2];     // (N,)
    // d_in[3] = true_targets: unused by the forward
    const float* prob = (const float*)d_in[4];   // (N,)
    const float* thr  = (const float*)d_in[5];   // scalar
    float* out = (float*)d_out;

    // workspace carve-up (all 256B-aligned)
    char* w = (char*)d_ws;
    auto alloc = [&](size_t bytes) {
        char* p = w;
        w += (bytes + 255) & ~(size_t)255;
        return p;
    };
    float* sq        = (float*)alloc(NROWS * sizeof(float));
    int*   pred_cls  = (int*)  alloc(NROWS * sizeof(int));
    int*   class_cnt = (int*)  alloc(CNUM * sizeof(int));
    int*   class_mem = (int*)  alloc((size_t)CNUM * MAXM * sizeof(int));
    float* part_v    = (float*)alloc((size_t)NROWS * SLICES * TOPK * sizeof(float));
    int*   part_i    = (int*)  alloc((size_t)NROWS * SLICES * TOPK * sizeof(int));
    float* top_v     = (float*)alloc((size_t)NROWS * TOPK * sizeof(float));
    int*   top_i     = (int*)  alloc((size_t)NROWS * TOPK * sizeof(int));
    float* row_loss  = (float*)alloc(NROWS * sizeof(float));
    int*   row_corr  = (int*)  alloc(NROWS * sizeof(int));

    rowsq_kernel<<<NROWS / 4, 256, 0, stream>>>(X, sq);
    predcls_kernel<<<NROWS / 4, 256, 0, stream>>>(P, pred_cls);
    classlist_kernel<<<2, 64, 0, stream>>>(tgt, class_cnt, class_mem);
    dist_topk_kernel<<<dim3(NROWS / BM, SLICES), 256, 0, stream>>>(X, sq, tgt, part_v, part_i);
    topk_merge_kernel<<<NROWS / 256, 256, 0, stream>>>(part_v, part_i, top_v, top_i);
    rowlogic_kernel<<<NROWS / 4, 256, 0, stream>>>(X, sq, prob, thr, tgt, pred_cls,
                                                   class_cnt, class_mem, top_v, top_i,
                                                   row_loss, row_corr);
    reduce_kernel<<<1, 256, 0, stream>>>(row_loss, row_corr, prob, thr, out);
}

// Round 2
// 783.352 us; speedup vs baseline: 2.4466x; 2.4466x over previous
//
#include <hip/hip_runtime.h>
#include <hip/hip_bf16.h>
#include <cstdint>
#include <cmath>

#define NROWS 4096
#define DIM   2048
#define CNUM  128
#define MARGIN_F 0.3f
#define TOPK 12
#define MAXM 256

// fallback-path tiling
#define BM 64
#define BN 64
#define BK 16
#define SLICES 8
#define COLS_PER_SLICE (NROWS / SLICES)

typedef __bf16 bf16x8 __attribute__((ext_vector_type(8)));
typedef float  f32x16 __attribute__((ext_vector_type(16)));

__device__ __forceinline__ uint32_t rnd_u32(uint32_t row, uint32_t k) {
    uint64_t x = ((uint64_t)row << 32) ^ (0x9E3779B97F4A7C15ULL * (uint64_t)(k + 1u));
    x ^= x >> 33; x *= 0xff51afd7ed558ccdULL;
    x ^= x >> 33; x *= 0xc4ceb9fe1a85ec53ULL;
    x ^= x >> 33;
    return (uint32_t)x;
}

// bf16 round-to-nearest-even from fp32 bits
__device__ __forceinline__ uint16_t bf16_rne(float x) {
    uint32_t u = __float_as_uint(x);
    return (uint16_t)((u + 0x7FFFu + ((u >> 16) & 1u)) >> 16);
}
__device__ __forceinline__ float bf16_to_f(uint16_t h) {
    return __uint_as_float((uint32_t)h << 16);
}

// ---------- kernel 1a: row sum of squares (one wave per row) ----------
__global__ void rowsq_kernel(const float* __restrict__ X, float* __restrict__ sq) {
    int wave = (blockIdx.x * blockDim.x + threadIdx.x) >> 6;
    int lane = threadIdx.x & 63;
    if (wave >= NROWS) return;
    const float4* xp = (const float4*)(X + (size_t)wave * DIM);
    float s = 0.f;
    for (int k = lane; k < DIM / 4; k += 64) {
        float4 v = xp[k];
        s += v.x * v.x + v.y * v.y + v.z * v.z + v.w * v.w;
    }
    for (int off = 32; off; off >>= 1) s += __shfl_xor(s, off, 64);
    if (lane == 0) sq[wave] = s;
}

// ---------- kernel 1b: pred_cls = argmax over C=128 (one wave per row) ----------
__global__ void predcls_kernel(const float* __restrict__ P, int* __restrict__ cls) {
    int row = (blockIdx.x * blockDim.x + threadIdx.x) >> 6;
    int lane = threadIdx.x & 63;
    if (row >= NROWS) return;
    const float* p = P + (size_t)row * CNUM;
    float v0 = p[lane]; int i0 = lane;
    float v1 = p[lane + 64];
    if (v1 > v0) { v0 = v1; i0 = lane + 64; }   // first-max semantics
    for (int off = 1; off < 64; off <<= 1) {
        float ov = __shfl_xor(v0, off, 64);
        int   oi = __shfl_xor(i0, off, 64);
        if (ov > v0 || (ov == v0 && oi < i0)) { v0 = ov; i0 = oi; }
    }
    if (lane == 0) cls[row] = i0;
}

// ---------- kernel 2: per-class member lists via wave ballot compaction ----------
__global__ void classlist_kernel(const int* __restrict__ tgt,
                                 int* __restrict__ cnt, int* __restrict__ members) {
    int c = (blockIdx.x * blockDim.x + threadIdx.x) >> 6;  // one wave per class
    int lane = threadIdx.x & 63;
    if (c >= CNUM) return;
    int k = 0;
    for (int base = 0; base < NROWS; base += 64) {
        int i = base + lane;
        bool m = (tgt[i] == c);
        unsigned long long mask = __ballot(m);
        if (m) {
            int pos = k + __popcll(mask & ((1ull << lane) - 1ull));
            if (pos < MAXM) members[c * MAXM + pos] = i;
        }
        k += __popcll(mask);
    }
    if (lane == 0) cnt[c] = (k < MAXM) ? k : MAXM;
}

// ---------- fast path: fp32 -> (hi, lo) bf16 split ----------
__global__ void convert_kernel(const float* __restrict__ X,
                               uint16_t* __restrict__ hi, uint16_t* __restrict__ lo) {
    int idx = blockIdx.x * blockDim.x + threadIdx.x;     // one float4 per thread
    float4 v = ((const float4*)X)[idx];
    ushort4 h, l;
    {
        h.x = bf16_rne(v.x); l.x = bf16_rne(v.x - bf16_to_f(h.x));
        h.y = bf16_rne(v.y); l.y = bf16_rne(v.y - bf16_to_f(h.y));
        h.z = bf16_rne(v.z); l.z = bf16_rne(v.z - bf16_to_f(h.z));
        h.w = bf16_rne(v.w); l.w = bf16_rne(v.w - bf16_to_f(h.w));
    }
    ((ushort4*)hi)[idx] = h;
    ((ushort4*)lo)[idx] = l;
}

// ---------- fast path: split-bf16 MFMA Gram -> masked squared-distance matrix ----------
// grid (32, 32); upper-triangle blocks only; 256 threads = 4 waves in 2x2 of 64x64.
// Each wave: 2x2 tiles of 32x32 via v_mfma_f32_32x32x16_bf16, direct global
// fragment loads (no LDS -> no bank conflicts, no barriers; L1 holds the 16 KB
// per-k-step working set).
__launch_bounds__(256)
__global__ void mfma_dist_kernel(const uint16_t* __restrict__ Xhi, const uint16_t* __restrict__ Xlo,
                                 const float* __restrict__ sq, const int* __restrict__ tgt,
                                 float* __restrict__ dist) {
    int br = blockIdx.x, bc = blockIdx.y;
    if (br > bc) return;                      // symmetry: mirror-store below
    int wave = threadIdx.x >> 6, lane = threadIdx.x & 63;
    int wr = wave >> 1, wc = wave & 1;
    int r0 = br * 128 + wr * 64, c0 = bc * 128 + wc * 64;
    int lm = lane & 31, lq = lane >> 5;

    f32x16 acc[2][2];
#pragma unroll
    for (int i = 0; i < 2; i++)
#pragma unroll
        for (int j = 0; j < 2; j++) acc[i][j] = 0.f;

    // per-lane fragment base pointers: A[m][k], m = tile_base + (lane&31), k-half = lane>>5
    const uint16_t* pah[2]; const uint16_t* pal[2];
    const uint16_t* pbh[2]; const uint16_t* pbl[2];
#pragma unroll
    for (int i = 0; i < 2; i++) {
        size_t ra = (size_t)(r0 + i * 32 + lm) * DIM + lq * 8;
        size_t rb = (size_t)(c0 + i * 32 + lm) * DIM + lq * 8;
        pah[i] = Xhi + ra; pal[i] = Xlo + ra;
        pbh[i] = Xhi + rb; pbl[i] = Xlo + rb;
    }

#pragma unroll 8
    for (int k = 0; k < DIM; k += 16) {
        bf16x8 ah[2], al[2], bh[2], bl[2];
#pragma unroll
        for (int i = 0; i < 2; i++) {
            ah[i] = *(const bf16x8*)(pah[i] + k);
            al[i] = *(const bf16x8*)(pal[i] + k);
            bh[i] = *(const bf16x8*)(pbh[i] + k);
            bl[i] = *(const bf16x8*)(pbl[i] + k);
        }
#pragma unroll
        for (int i = 0; i < 2; i++)
#pragma unroll
            for (int j = 0; j < 2; j++) {
                acc[i][j] = __builtin_amdgcn_mfma_f32_32x32x16_bf16(ah[i], bh[j], acc[i][j], 0, 0, 0);
                acc[i][j] = __builtin_amdgcn_mfma_f32_32x32x16_bf16(ah[i], bl[j], acc[i][j], 0, 0, 0);
                acc[i][j] = __builtin_amdgcn_mfma_f32_32x32x16_bf16(al[i], bh[j], acc[i][j], 0, 0, 0);
            }
    }

    // epilogue: C/D layout (32x32): col = lane&31, row = (reg&3) + 8*(reg>>2) + 4*(lane>>5)
#pragma unroll
    for (int ti = 0; ti < 2; ti++)
#pragma unroll
        for (int tj = 0; tj < 2; tj++) {
#pragma unroll
            for (int reg = 0; reg < 16; reg++) {
                int row = r0 + ti * 32 + (reg & 3) + 8 * (reg >> 2) + 4 * lq;
                int col = c0 + tj * 32 + lm;
                float d2 = sq[row] + sq[col] - 2.f * acc[ti][tj][reg];
                if (tgt[row] == tgt[col]) d2 = INFINITY;  // positives (incl. diagonal)
                dist[(size_t)row * NROWS + col] = d2;
                dist[(size_t)col * NROWS + row] = d2;     // mirror (diag blocks: benign dup)
            }
        }
}

// ---------- fast path: per-row top-12 over materialized dist ----------
__launch_bounds__(256)
__global__ void topk_kernel(const float* __restrict__ dist,
                            float* __restrict__ top_v, int* __restrict__ top_i) {
    __shared__ float sv[4][64 * TOPK];
    __shared__ int   si[4][64 * TOPK];
    int wave = threadIdx.x >> 6, lane = threadIdx.x & 63;
    int row = blockIdx.x * 4 + wave;
    const float* d = dist + (size_t)row * NROWS;

    float lv[TOPK]; int li[TOPK];
#pragma unroll
    for (int k = 0; k < TOPK; k++) { lv[k] = INFINITY; li[k] = -1; }
    for (int c = lane; c < NROWS; c += 64) {
        float v = d[c];
        if (v < lv[TOPK - 1]) {
            float nv = v; int ni = c;
#pragma unroll
            for (int p = 0; p < TOPK; p++) {
                if (nv < lv[p]) {
                    float tv = lv[p]; int ti = li[p];
                    lv[p] = nv; li[p] = ni;
                    nv = tv; ni = ti;
                }
            }
        }
    }
#pragma unroll
    for (int k = 0; k < TOPK; k++) {
        sv[wave][lane * TOPK + k] = lv[k];
        si[wave][lane * TOPK + k] = li[k];
    }
    // 12-round tournament over the 64 sorted heads (wave-private LDS, no barrier)
    int head = 0;
    for (int t = 0; t < TOPK; t++) {
        float hv = (head < TOPK) ? sv[wave][lane * TOPK + head] : INFINITY;
        int   hc = (head < TOPK) ? si[wave][lane * TOPK + head] : -1;
        int   hl = lane;
        for (int off = 32; off; off >>= 1) {
            float ov = __shfl_xor(hv, off, 64);
            int   oc = __shfl_xor(hc, off, 64);
            int   ol = __shfl_xor(hl, off, 64);
            if (ov < hv || (ov == hv && ol < hl)) { hv = ov; hc = oc; hl = ol; }
        }
        if (lane == 0) {
            top_v[(size_t)row * TOPK + t] = hv;
            top_i[(size_t)row * TOPK + t] = hc;
        }
        if (lane == hl) head++;
    }
}

// ---------- fallback path (proven R1): fused fp32 GEMM + per-row top-12 ----------
__launch_bounds__(256)
__global__ void dist_topk_kernel(const float* __restrict__ X, const float* __restrict__ sq,
                                 const int* __restrict__ tgt,
                                 float* __restrict__ part_v, int* __restrict__ part_i) {
    __shared__ float As[BK][BM];
    __shared__ float Bs[BK][BN];
    __shared__ float Cs[BM][BN + 1];
    __shared__ float sqA[BM], sqB[BN];
    __shared__ int   tgA[BM], tgB[BN];

    int rowBase = blockIdx.x * BM;
    int slice = blockIdx.y;
    int tid = threadIdx.x;
    int tx = tid & 15, ty = tid >> 4;

    if (tid < BM) { sqA[tid] = sq[rowBase + tid]; tgA[tid] = tgt[rowBase + tid]; }

    float lv[TOPK]; int li[TOPK];
#pragma unroll
    for (int k = 0; k < TOPK; k++) { lv[k] = INFINITY; li[k] = -1; }

    for (int jt = 0; jt < COLS_PER_SLICE / BN; jt++) {
        int colBase = slice * COLS_PER_SLICE + jt * BN;
        __syncthreads();
        if (tid < BN) { sqB[tid] = sq[colBase + tid]; tgB[tid] = tgt[colBase + tid]; }

        float acc[4][4] = {};
        for (int kb = 0; kb < DIM; kb += BK) {
            int r  = tid >> 2;
            int kk = (tid & 3) * 4;
            float4 va = *(const float4*)(X + (size_t)(rowBase + r) * DIM + kb + kk);
            As[kk + 0][r] = va.x; As[kk + 1][r] = va.y; As[kk + 2][r] = va.z; As[kk + 3][r] = va.w;
            float4 vb = *(const float4*)(X + (size_t)(colBase + r) * DIM + kb + kk);
            Bs[kk + 0][r] = vb.x; Bs[kk + 1][r] = vb.y; Bs[kk + 2][r] = vb.z; Bs[kk + 3][r] = vb.w;
            __syncthreads();
#pragma unroll
            for (int k = 0; k < BK; k++) {
                float a[4], b[4];
                *(float4*)a = *(const float4*)&As[k][ty * 4];
                *(float4*)b = *(const float4*)&Bs[k][tx * 4];
#pragma unroll
                for (int i2 = 0; i2 < 4; i2++)
#pragma unroll
                    for (int j2 = 0; j2 < 4; j2++)
                        acc[i2][j2] += a[i2] * b[j2];
            }
            __syncthreads();
        }
#pragma unroll
        for (int i2 = 0; i2 < 4; i2++) {
            int r = ty * 4 + i2;
#pragma unroll
            for (int j2 = 0; j2 < 4; j2++) {
                int c = tx * 4 + j2;
                float d2 = sqA[r] + sqB[c] - 2.f * acc[i2][j2];
                if (tgA[r] == tgB[c]) d2 = INFINITY;
                Cs[r][c] = d2;
            }
        }
        __syncthreads();
        if (tid < BM) {
            int r = tid;
            for (int c = 0; c < BN; c++) {
                float v = Cs[r][c];
                if (v < lv[TOPK - 1]) {
                    float nv = v; int ni = colBase + c;
#pragma unroll
                    for (int p = 0; p < TOPK; p++) {
                        if (nv < lv[p]) {
                            float tv = lv[p]; int ti = li[p];
                            lv[p] = nv; li[p] = ni;
                            nv = tv; ni = ti;
                        }
                    }
                }
            }
        }
    }
    if (tid < BM) {
        int r = tid;
#pragma unroll
        for (int k = 0; k < TOPK; k++) {
            size_t o = ((size_t)(rowBase + r) * SLICES + slice) * TOPK + k;
            part_v[o] = lv[k];
            part_i[o] = li[k];
        }
    }
}

__global__ void topk_merge_kernel(const float* __restrict__ part_v, const int* __restrict__ part_i,
                                  float* __restrict__ top_v, int* __restrict__ top_i) {
    int row = blockIdx.x * blockDim.x + threadIdx.x;
    if (row >= NROWS) return;
    float lv[TOPK]; int li[TOPK];
#pragma unroll
    for (int k = 0; k < TOPK; k++) { lv[k] = INFINITY; li[k] = -1; }
    for (int s = 0; s < SLICES; s++) {
        for (int k = 0; k < TOPK; k++) {
            size_t o = ((size_t)row * SLICES + s) * TOPK + k;
            float v = part_v[o];
            if (!(v < lv[TOPK - 1])) break;
            int idx = part_i[o];
            float nv = v; int ni = idx;
#pragma unroll
            for (int p = 0; p < TOPK; p++) {
                if (nv < lv[p]) {
                    float tv = lv[p]; int ti = li[p];
                    lv[p] = nv; li[p] = ni;
                    nv = tv; ni = ti;
                }
            }
        }
    }
#pragma unroll
    for (int k = 0; k < TOPK; k++) {
        top_v[(size_t)row * TOPK + k] = lv[k];
        top_i[(size_t)row * TOPK + k] = li[k];
    }
}

// ---------- kernel 5: per-row triplet logic (one wave per row) ----------
__global__ void rowlogic_kernel(const float* __restrict__ X, const float* __restrict__ sq,
                                const float* __restrict__ prob, const float* __restrict__ thr_p,
                                const int* __restrict__ tgt, const int* __restrict__ pred_cls,
                                const int* __restrict__ class_cnt, const int* __restrict__ class_mem,
                                const float* __restrict__ top_v, const int* __restrict__ top_i,
                                float* __restrict__ row_loss, int* __restrict__ row_corr) {
    int i = (blockIdx.x * blockDim.x + threadIdx.x) >> 6;
    int lane = threadIdx.x & 63;
    if (i >= NROWS) return;
    float thr = *thr_p;

    int c = tgt[i];
    int cc = class_cnt[c];
    const int* mem = class_mem + c * MAXM;

    int pos_i = 0;
    for (int k = 0; k < cc; k++) { if (mem[k] == i) { pos_i = k; break; } }

    int rp = 0;
    if (cc > 1) {
        uint32_t r = rnd_u32((uint32_t)i, 0x9111u) % (uint32_t)(cc - 1);
        if ((int)r >= pos_i) r++;
        rp = mem[r];
    }

    int hn = top_i[(size_t)i * TOPK + 0];
    float an0 = sqrtf(fmaxf(top_v[(size_t)i * TOPK + 0], 1e-12f));
    bool p_neg = prob[hn] >= thr;
    bool is_FN = (pred_cls[hn] == c);

    int sel = 11;
    for (int k = 1; k <= 11; k++) {
        int cd = top_i[(size_t)i * TOPK + k];
        if (prob[cd] >= thr) { sel = k; break; }
    }
    float anB = sqrtf(fmaxf(top_v[(size_t)i * TOPK + sel], 1e-12f));

    int first_valid = -1, last_draw = 0;
    for (int k = 0; k < 6; k++) {
        uint32_t r = rnd_u32((uint32_t)i, 0xD000u + (uint32_t)k) % (uint32_t)(cc > 0 ? cc : 1);
        int dk = mem[r];
        last_draw = dk;
        if (first_valid < 0 && dk != i && prob[dk] >= thr) first_valid = dk;
    }
    int rp_new = (first_valid >= 0) ? first_valid : last_draw;
    bool p_pos = prob[rp] >= thr;

    const float4* xi = (const float4*)(X + (size_t)i * DIM);
    const float4* xr = (const float4*)(X + (size_t)rp * DIM);
    const float4* xn = (const float4*)(X + (size_t)rp_new * DIM);
    float s1 = 0.f, s2 = 0.f;
    for (int k = lane; k < DIM / 4; k += 64) {
        float4 a = xi[k], b = xr[k], d = xn[k];
        s1 += a.x * b.x + a.y * b.y + a.z * b.z + a.w * b.w;
        s2 += a.x * d.x + a.y * d.y + a.z * d.z + a.w * d.w;
    }
    for (int off = 32; off; off >>= 1) {
        s1 += __shfl_xor(s1, off, 64);
        s2 += __shfl_xor(s2, off, 64);
    }
    if (lane == 0) {
        float ap0 = sqrtf(fmaxf(sq[i] + sq[rp]     - 2.f * s1, 1e-12f));
        float apC = sqrtf(fmaxf(sq[i] + sq[rp_new] - 2.f * s2, 1e-12f));
        float apB = (ap0 + an0) * 0.5f;
        float anC = (ap0 + an0) * 0.5f;
        bool useB = p_pos && !p_neg && is_FN;
        bool useC = (!p_pos && p_neg) || (!p_pos && !p_neg && !is_FN);
        bool inverse = !p_pos && !p_neg && is_FN;
        float ap = useB ? apB : (useC ? apC : ap0);
        float an = useB ? anB : (useC ? anC : an0);
        float pl = inverse ? fmaxf(an - ap + MARGIN_F, 0.f)
                           : fmaxf(ap - an + MARGIN_F, 0.f);
        bool conf = prob[i] >= thr;
        row_loss[i] = conf ? pl : 0.f;
        row_corr[i] = (conf && (an >= ap)) ? 1 : 0;
    }
}

// ---------- kernel 6: final reduction ----------
__global__ void reduce_kernel(const float* __restrict__ row_loss, const int* __restrict__ row_corr,
                              const float* __restrict__ prob, const float* __restrict__ thr_p,
                              float* __restrict__ out) {
    __shared__ float sl[256];
    __shared__ int   sc[256];
    __shared__ int   sn[256];
    float thr = *thr_p;
    int tid = threadIdx.x;
    float l = 0.f; int corr = 0, cnt = 0;
    for (int i = tid; i < NROWS; i += 256) {
        l += row_loss[i];
        corr += row_corr[i];
        cnt += (prob[i] >= thr) ? 1 : 0;
    }
    sl[tid] = l; sc[tid] = corr; sn[tid] = cnt;
    __syncthreads();
    for (int off = 128; off; off >>= 1) {
        if (tid < off) {
            sl[tid] += sl[tid + off];
            sc[tid] += sc[tid + off];
            sn[tid] += sn[tid + off];
        }
        __syncthreads();
    }
    if (tid == 0) {
        int cn = sn[0];
        float loss = (cn > 0) ? (sl[0] / (float)(cn > 1 ? cn : 1)) : 0.f;
        out[0] = loss;
        out[1] = (float)sc[0];
        out[2] = (float)cn;
    }
}

extern "C" void kernel_launch(void* const* d_in, const int* in_sizes, int n_in,
                              void* d_out, int out_size, void* d_ws, size_t ws_size,
                              hipStream_t stream) {
    const float* X    = (const float*)d_in[0];
    const float* P    = (const float*)d_in[1];
    const int*   tgt  = (const int*)d_in[2];
    const float* prob = (const float*)d_in[4];
    const float* thr  = (const float*)d_in[5];
    float* out = (float*)d_out;

    char* w = (char*)d_ws;
    auto alloc = [&](size_t bytes) {
        char* p = w;
        w += (bytes + 255) & ~(size_t)255;
        return p;
    };
    float* sq        = (float*)alloc(NROWS * sizeof(float));
    int*   pred_cls  = (int*)  alloc(NROWS * sizeof(int));
    int*   class_cnt = (int*)  alloc(CNUM * sizeof(int));
    int*   class_mem = (int*)  alloc((size_t)CNUM * MAXM * sizeof(int));
    float* top_v     = (float*)alloc((size_t)NROWS * TOPK * sizeof(float));
    int*   top_i     = (int*)  alloc((size_t)NROWS * TOPK * sizeof(int));
    float* row_loss  = (float*)alloc(NROWS * sizeof(float));
    int*   row_corr  = (int*)  alloc(NROWS * sizeof(int));
    char*  var_base  = w;

    // fast-path extra requirement: Xhi + Xlo (2 x 16.78 MB) + dist (64 MB)
    size_t fast_need = (size_t)NROWS * DIM * 2 * 2 + (size_t)NROWS * NROWS * 4 + (1 << 20);
    bool fast = ((size_t)(var_base - (char*)d_ws) + fast_need) <= ws_size;

    rowsq_kernel<<<NROWS / 4, 256, 0, stream>>>(X, sq);
    predcls_kernel<<<NROWS / 4, 256, 0, stream>>>(P, pred_cls);
    classlist_kernel<<<CNUM / 4, 256, 0, stream>>>(tgt, class_cnt, class_mem);

    if (fast) {
        uint16_t* Xhi = (uint16_t*)alloc((size_t)NROWS * DIM * 2);
        uint16_t* Xlo = (uint16_t*)alloc((size_t)NROWS * DIM * 2);
        float*    dist = (float*)alloc((size_t)NROWS * NROWS * 4);
        convert_kernel<<<(NROWS * DIM / 4) / 256, 256, 0, stream>>>(X, Xhi, Xlo);
        mfma_dist_kernel<<<dim3(32, 32), 256, 0, stream>>>(Xhi, Xlo, sq, tgt, dist);
        topk_kernel<<<NROWS / 4, 256, 0, stream>>>(dist, top_v, top_i);
    } else {
        float* part_v = (float*)alloc((size_t)NROWS * SLICES * TOPK * sizeof(float));
        int*   part_i = (int*)  alloc((size_t)NROWS * SLICES * TOPK * sizeof(int));
        dist_topk_kernel<<<dim3(NROWS / BM, SLICES), 256, 0, stream>>>(X, sq, tgt, part_v, part_i);
        topk_merge_kernel<<<NROWS / 256, 256, 0, stream>>>(part_v, part_i, top_v, top_i);
    }

    rowlogic_kernel<<<NROWS / 4, 256, 0, stream>>>(X, sq, prob, thr, tgt, pred_cls,
                                                   class_cnt, class_mem, top_v, top_i,
                                                   row_loss, row_corr);
    reduce_kernel<<<1, 256, 0, stream>>>(row_loss, row_corr, prob, thr, out);
}

// Round 3
// 366.797 us; speedup vs baseline: 5.2250x; 2.1357x over previous
//
#include <hip/hip_runtime.h>
#include <hip/hip_bf16.h>
#include <cstdint>
#include <cmath>

#define NROWS 4096
#define DIM   2048
#define CNUM  128
#define MARGIN_F 0.3f
#define TOPK 12
#define MAXM 256
#define GBK 32          // K-tile (f16 elements)

// fallback-path tiling
#define BM 64
#define BN 64
#define BK 16
#define SLICES 8
#define COLS_PER_SLICE (NROWS / SLICES)

typedef _Float16 f16x8 __attribute__((ext_vector_type(8)));
typedef float    f32x4 __attribute__((ext_vector_type(4)));

// async global->LDS, 16 B per lane; lds dest = wave-uniform base + lane*16
#define GLD_LDS16(g, l)                                                        \
    __builtin_amdgcn_global_load_lds(                                          \
        (const __attribute__((address_space(1))) uint32_t*)(g),                \
        (__attribute__((address_space(3))) uint32_t*)(l), 16, 0, 0)

__device__ __forceinline__ uint32_t rnd_u32(uint32_t row, uint32_t k) {
    uint64_t x = ((uint64_t)row << 32) ^ (0x9E3779B97F4A7C15ULL * (uint64_t)(k + 1u));
    x ^= x >> 33; x *= 0xff51afd7ed558ccdULL;
    x ^= x >> 33; x *= 0xc4ceb9fe1a85ec53ULL;
    x ^= x >> 33;
    return (uint32_t)x;
}

// ---------- kernel 1a: row sum of squares (one wave per row) ----------
__global__ void rowsq_kernel(const float* __restrict__ X, float* __restrict__ sq) {
    int wave = (blockIdx.x * blockDim.x + threadIdx.x) >> 6;
    int lane = threadIdx.x & 63;
    if (wave >= NROWS) return;
    const float4* xp = (const float4*)(X + (size_t)wave * DIM);
    float s = 0.f;
    for (int k = lane; k < DIM / 4; k += 64) {
        float4 v = xp[k];
        s += v.x * v.x + v.y * v.y + v.z * v.z + v.w * v.w;
    }
    for (int off = 32; off; off >>= 1) s += __shfl_xor(s, off, 64);
    if (lane == 0) sq[wave] = s;
}

// ---------- kernel 1b: pred_cls = argmax over C=128 (one wave per row) ----------
__global__ void predcls_kernel(const float* __restrict__ P, int* __restrict__ cls) {
    int row = (blockIdx.x * blockDim.x + threadIdx.x) >> 6;
    int lane = threadIdx.x & 63;
    if (row >= NROWS) return;
    const float* p = P + (size_t)row * CNUM;
    float v0 = p[lane]; int i0 = lane;
    float v1 = p[lane + 64];
    if (v1 > v0) { v0 = v1; i0 = lane + 64; }
    for (int off = 1; off < 64; off <<= 1) {
        float ov = __shfl_xor(v0, off, 64);
        int   oi = __shfl_xor(i0, off, 64);
        if (ov > v0 || (ov == v0 && oi < i0)) { v0 = ov; i0 = oi; }
    }
    if (lane == 0) cls[row] = i0;
}

// ---------- kernel 2: per-class member lists via wave ballot compaction ----------
__global__ void classlist_kernel(const int* __restrict__ tgt,
                                 int* __restrict__ cnt, int* __restrict__ members) {
    int c = (blockIdx.x * blockDim.x + threadIdx.x) >> 6;
    int lane = threadIdx.x & 63;
    if (c >= CNUM) return;
    int k = 0;
    for (int base = 0; base < NROWS; base += 64) {
        int i = base + lane;
        bool m = (tgt[i] == c);
        unsigned long long mask = __ballot(m);
        if (m) {
            int pos = k + __popcll(mask & ((1ull << lane) - 1ull));
            if (pos < MAXM) members[c * MAXM + pos] = i;
        }
        k += __popcll(mask);
    }
    if (lane == 0) cnt[c] = (k < MAXM) ? k : MAXM;
}

// ---------- fast path: fp32 -> f16 convert ----------
__global__ void convert_kernel(const float* __restrict__ X, _Float16* __restrict__ Xh) {
    int idx = blockIdx.x * blockDim.x + threadIdx.x;   // one float4 per thread
    float4 v = ((const float4*)X)[idx];
    _Float16 h[4] = { (_Float16)v.x, (_Float16)v.y, (_Float16)v.z, (_Float16)v.w };
    ((uint2*)Xh)[idx] = *(uint2*)h;
}

// ---------- fast path: m97-style f16 MFMA Gram -> masked squared-distance ----------
// grid: 528 upper-triangle 128x128 tiles; 256 threads = 4 waves, each a 64x64
// quadrant as 4x4 of v_mfma_f32_16x16x32_f16. LDS-staged via global_load_lds
// width=16, single-buffered 2-barrier K-loop (m97 structure, 874 TF proven).
__launch_bounds__(256)
__global__ void mfma_dist_kernel(const _Float16* __restrict__ Xh,
                                 const float* __restrict__ sq, const int* __restrict__ tgt,
                                 float* __restrict__ dist) {
    __shared__ _Float16 Ah[128 * GBK];   // row-major [128][32]
    __shared__ _Float16 Bh[128 * GBK];
    __shared__ float    trb[4][16 * 17]; // per-wave transpose buffer
    __shared__ float    sqA[128], sqB[128];
    __shared__ int      tgA[128], tgB[128];

    // decode linear block -> upper-triangle (br, bc)
    int b = blockIdx.x;
    int br = 0, S = 0;
    while (b >= S + (32 - br)) { S += 32 - br; br++; }
    int bc = br + (b - S);

    int r0 = br * 128, c0 = bc * 128;
    int tid = threadIdx.x;
    int wave = tid >> 6, lane = tid & 63;
    int wr = wave >> 1, wc = wave & 1;

    if (tid < 128) { sqA[tid] = sq[r0 + tid]; tgA[tid] = tgt[r0 + tid]; }
    else { int t = tid - 128; sqB[t] = sq[c0 + t]; tgB[t] = tgt[c0 + t]; }

    f32x4 acc[4][4];
#pragma unroll
    for (int i = 0; i < 4; i++)
#pragma unroll
        for (int j = 0; j < 4; j++) acc[i][j] = (f32x4)0.f;

    // staging: wave w loads A rows [w*16, w*16+16) and [(w+4)*16, ...), same for B.
    int sr = lane >> 2;            // 0..15 row within slot
    int sc = (lane & 3) * 8;       // 0,8,16,24 col
    const _Float16* gA0 = Xh + (size_t)(r0 + wave * 16 + sr) * DIM + sc;
    const _Float16* gA1 = Xh + (size_t)(r0 + (wave + 4) * 16 + sr) * DIM + sc;
    const _Float16* gB0 = Xh + (size_t)(c0 + wave * 16 + sr) * DIM + sc;
    const _Float16* gB1 = Xh + (size_t)(c0 + (wave + 4) * 16 + sr) * DIM + sc;
    _Float16* lA0 = &Ah[(wave)     * 16 * GBK];
    _Float16* lA1 = &Ah[(wave + 4) * 16 * GBK];
    _Float16* lB0 = &Bh[(wave)     * 16 * GBK];
    _Float16* lB1 = &Bh[(wave + 4) * 16 * GBK];

    int fr = lane & 15, fq = lane >> 4;
    const int fk = fq * 8;

    for (int kb = 0; kb < DIM; kb += GBK) {
        __syncthreads();                       // LDS reuse: prior fragment reads done
        GLD_LDS16(gA0 + kb, lA0);
        GLD_LDS16(gA1 + kb, lA1);
        GLD_LDS16(gB0 + kb, lB0);
        GLD_LDS16(gB1 + kb, lB1);
        __syncthreads();                       // drains vmcnt (loads landed in LDS)

        f16x8 af[4], bfr[4];
#pragma unroll
        for (int i = 0; i < 4; i++)
            af[i] = *(const f16x8*)&Ah[(wr * 64 + i * 16 + fr) * GBK + fk];
#pragma unroll
        for (int j = 0; j < 4; j++)
            bfr[j] = *(const f16x8*)&Bh[(wc * 64 + j * 16 + fr) * GBK + fk];
#pragma unroll
        for (int i = 0; i < 4; i++)
#pragma unroll
            for (int j = 0; j < 4; j++)
                acc[i][j] = __builtin_amdgcn_mfma_f32_16x16x32_f16(af[i], bfr[j], acc[i][j], 0, 0, 0);
    }

    // epilogue: d2 = sqA+sqB-2*dot, mask positives; direct store + LDS-transposed mirror
    float* tb = trb[wave];
#pragma unroll
    for (int i = 0; i < 4; i++) {
#pragma unroll
        for (int j = 0; j < 4; j++) {
            int lcol = wc * 64 + j * 16 + fr;
            float d[4];
#pragma unroll
            for (int r = 0; r < 4; r++) {
                int lrow = wr * 64 + i * 16 + fq * 4 + r;
                float v = sqA[lrow] + sqB[lcol] - 2.f * acc[i][j][r];
                if (tgA[lrow] == tgB[lcol]) v = INFINITY;
                d[r] = v;
                dist[(size_t)(r0 + lrow) * NROWS + (c0 + lcol)] = v;
            }
            if (br != bc) {
                // tb[tcol][trow] = v ; trow = fq*4+r, tcol = fr
#pragma unroll
                for (int r = 0; r < 4; r++) tb[fr * 17 + fq * 4 + r] = d[r];
                // read transposed, store coalesced along original-row axis
#pragma unroll
                for (int r = 0; r < 4; r++) {
                    float v = tb[(fq * 4 + r) * 17 + fr];
                    int grow = c0 + wc * 64 + j * 16 + fq * 4 + r;   // mirror row
                    int gcol = r0 + wr * 64 + i * 16 + fr;           // mirror col
                    dist[(size_t)grow * NROWS + gcol] = v;
                }
            }
        }
    }
}

// ---------- fast path: per-row top-12 over materialized dist (float4 loads) ----------
__launch_bounds__(256)
__global__ void topk_kernel(const float* __restrict__ dist,
                            float* __restrict__ top_v, int* __restrict__ top_i) {
    __shared__ float sv[4][64 * TOPK];
    __shared__ int   si[4][64 * TOPK];
    int wave = threadIdx.x >> 6, lane = threadIdx.x & 63;
    int row = blockIdx.x * 4 + wave;
    const float4* d = (const float4*)(dist + (size_t)row * NROWS);

    float lv[TOPK]; int li[TOPK];
#pragma unroll
    for (int k = 0; k < TOPK; k++) { lv[k] = INFINITY; li[k] = -1; }

    for (int c4 = lane; c4 < NROWS / 4; c4 += 64) {
        float4 v4 = d[c4];
        float vv[4] = { v4.x, v4.y, v4.z, v4.w };
#pragma unroll
        for (int t = 0; t < 4; t++) {
            float v = vv[t];
            if (v < lv[TOPK - 1]) {
                float nv = v; int ni = c4 * 4 + t;
#pragma unroll
                for (int p = 0; p < TOPK; p++) {
                    if (nv < lv[p]) {
                        float tv = lv[p]; int ti = li[p];
                        lv[p] = nv; li[p] = ni;
                        nv = tv; ni = ti;
                    }
                }
            }
        }
    }
#pragma unroll
    for (int k = 0; k < TOPK; k++) {
        sv[wave][lane * TOPK + k] = lv[k];
        si[wave][lane * TOPK + k] = li[k];
    }
    int head = 0;
    for (int t = 0; t < TOPK; t++) {
        float hv = (head < TOPK) ? sv[wave][lane * TOPK + head] : INFINITY;
        int   hc = (head < TOPK) ? si[wave][lane * TOPK + head] : -1;
        int   hl = lane;
        for (int off = 32; off; off >>= 1) {
            float ov = __shfl_xor(hv, off, 64);
            int   oc = __shfl_xor(hc, off, 64);
            int   ol = __shfl_xor(hl, off, 64);
            if (ov < hv || (ov == hv && ol < hl)) { hv = ov; hc = oc; hl = ol; }
        }
        if (lane == 0) {
            top_v[(size_t)row * TOPK + t] = hv;
            top_i[(size_t)row * TOPK + t] = hc;
        }
        if (lane == hl) head++;
    }
}

// ---------- fallback path (proven R1): fused fp32 GEMM + per-row top-12 ----------
__launch_bounds__(256)
__global__ void dist_topk_kernel(const float* __restrict__ X, const float* __restrict__ sq,
                                 const int* __restrict__ tgt,
                                 float* __restrict__ part_v, int* __restrict__ part_i) {
    __shared__ float As[BK][BM];
    __shared__ float Bs[BK][BN];
    __shared__ float Cs[BM][BN + 1];
    __shared__ float sqA[BM], sqB[BN];
    __shared__ int   tgA[BM], tgB[BN];

    int rowBase = blockIdx.x * BM;
    int slice = blockIdx.y;
    int tid = threadIdx.x;
    int tx = tid & 15, ty = tid >> 4;

    if (tid < BM) { sqA[tid] = sq[rowBase + tid]; tgA[tid] = tgt[rowBase + tid]; }

    float lv[TOPK]; int li[TOPK];
#pragma unroll
    for (int k = 0; k < TOPK; k++) { lv[k] = INFINITY; li[k] = -1; }

    for (int jt = 0; jt < COLS_PER_SLICE / BN; jt++) {
        int colBase = slice * COLS_PER_SLICE + jt * BN;
        __syncthreads();
        if (tid < BN) { sqB[tid] = sq[colBase + tid]; tgB[tid] = tgt[colBase + tid]; }

        float acc[4][4] = {};
        for (int kb = 0; kb < DIM; kb += BK) {
            int r  = tid >> 2;
            int kk = (tid & 3) * 4;
            float4 va = *(const float4*)(X + (size_t)(rowBase + r) * DIM + kb + kk);
            As[kk + 0][r] = va.x; As[kk + 1][r] = va.y; As[kk + 2][r] = va.z; As[kk + 3][r] = va.w;
            float4 vb = *(const float4*)(X + (size_t)(colBase + r) * DIM + kb + kk);
            Bs[kk + 0][r] = vb.x; Bs[kk + 1][r] = vb.y; Bs[kk + 2][r] = vb.z; Bs[kk + 3][r] = vb.w;
            __syncthreads();
#pragma unroll
            for (int k = 0; k < BK; k++) {
                float a[4], b[4];
                *(float4*)a = *(const float4*)&As[k][ty * 4];
                *(float4*)b = *(const float4*)&Bs[k][tx * 4];
#pragma unroll
                for (int i2 = 0; i2 < 4; i2++)
#pragma unroll
                    for (int j2 = 0; j2 < 4; j2++)
                        acc[i2][j2] += a[i2] * b[j2];
            }
            __syncthreads();
        }
#pragma unroll
        for (int i2 = 0; i2 < 4; i2++) {
            int r = ty * 4 + i2;
#pragma unroll
            for (int j2 = 0; j2 < 4; j2++) {
                int c = tx * 4 + j2;
                float d2 = sqA[r] + sqB[c] - 2.f * acc[i2][j2];
                if (tgA[r] == tgB[c]) d2 = INFINITY;
                Cs[r][c] = d2;
            }
        }
        __syncthreads();
        if (tid < BM) {
            int r = tid;
            for (int c = 0; c < BN; c++) {
                float v = Cs[r][c];
                if (v < lv[TOPK - 1]) {
                    float nv = v; int ni = colBase + c;
#pragma unroll
                    for (int p = 0; p < TOPK; p++) {
                        if (nv < lv[p]) {
                            float tv = lv[p]; int ti = li[p];
                            lv[p] = nv; li[p] = ni;
                            nv = tv; ni = ti;
                        }
                    }
                }
            }
        }
    }
    if (tid < BM) {
        int r = tid;
#pragma unroll
        for (int k = 0; k < TOPK; k++) {
            size_t o = ((size_t)(rowBase + r) * SLICES + slice) * TOPK + k;
            part_v[o] = lv[k];
            part_i[o] = li[k];
        }
    }
}

__global__ void topk_merge_kernel(const float* __restrict__ part_v, const int* __restrict__ part_i,
                                  float* __restrict__ top_v, int* __restrict__ top_i) {
    int row = blockIdx.x * blockDim.x + threadIdx.x;
    if (row >= NROWS) return;
    float lv[TOPK]; int li[TOPK];
#pragma unroll
    for (int k = 0; k < TOPK; k++) { lv[k] = INFINITY; li[k] = -1; }
    for (int s = 0; s < SLICES; s++) {
        for (int k = 0; k < TOPK; k++) {
            size_t o = ((size_t)row * SLICES + s) * TOPK + k;
            float v = part_v[o];
            if (!(v < lv[TOPK - 1])) break;
            int idx = part_i[o];
            float nv = v; int ni = idx;
#pragma unroll
            for (int p = 0; p < TOPK; p++) {
                if (nv < lv[p]) {
                    float tv = lv[p]; int ti = li[p];
                    lv[p] = nv; li[p] = ni;
                    nv = tv; ni = ti;
                }
            }
        }
    }
#pragma unroll
    for (int k = 0; k < TOPK; k++) {
        top_v[(size_t)row * TOPK + k] = lv[k];
        top_i[(size_t)row * TOPK + k] = li[k];
    }
}

// ---------- kernel 5: per-row triplet logic (one wave per row) ----------
__global__ void rowlogic_kernel(const float* __restrict__ X, const float* __restrict__ sq,
                                const float* __restrict__ prob, const float* __restrict__ thr_p,
                                const int* __restrict__ tgt, const int* __restrict__ pred_cls,
                                const int* __restrict__ class_cnt, const int* __restrict__ class_mem,
                                const float* __restrict__ top_v, const int* __restrict__ top_i,
                                float* __restrict__ row_loss, int* __restrict__ row_corr) {
    int i = (blockIdx.x * blockDim.x + threadIdx.x) >> 6;
    int lane = threadIdx.x & 63;
    if (i >= NROWS) return;
    float thr = *thr_p;

    int c = tgt[i];
    int cc = class_cnt[c];
    const int* mem = class_mem + c * MAXM;

    int pos_i = 0;
    for (int k = 0; k < cc; k++) { if (mem[k] == i) { pos_i = k; break; } }

    int rp = 0;
    if (cc > 1) {
        uint32_t r = rnd_u32((uint32_t)i, 0x9111u) % (uint32_t)(cc - 1);
        if ((int)r >= pos_i) r++;
        rp = mem[r];
    }

    int hn = top_i[(size_t)i * TOPK + 0];
    float an0 = sqrtf(fmaxf(top_v[(size_t)i * TOPK + 0], 1e-12f));
    bool p_neg = prob[hn] >= thr;
    bool is_FN = (pred_cls[hn] == c);

    int sel = 11;
    for (int k = 1; k <= 11; k++) {
        int cd = top_i[(size_t)i * TOPK + k];
        if (prob[cd] >= thr) { sel = k; break; }
    }
    float anB = sqrtf(fmaxf(top_v[(size_t)i * TOPK + sel], 1e-12f));

    int first_valid = -1, last_draw = 0;
    for (int k = 0; k < 6; k++) {
        uint32_t r = rnd_u32((uint32_t)i, 0xD000u + (uint32_t)k) % (uint32_t)(cc > 0 ? cc : 1);
        int dk = mem[r];
        last_draw = dk;
        if (first_valid < 0 && dk != i && prob[dk] >= thr) first_valid = dk;
    }
    int rp_new = (first_valid >= 0) ? first_valid : last_draw;
    bool p_pos = prob[rp] >= thr;

    const float4* xi = (const float4*)(X + (size_t)i * DIM);
    const float4* xr = (const float4*)(X + (size_t)rp * DIM);
    const float4* xn = (const float4*)(X + (size_t)rp_new * DIM);
    float s1 = 0.f, s2 = 0.f;
    for (int k = lane; k < DIM / 4; k += 64) {
        float4 a = xi[k], b = xr[k], d = xn[k];
        s1 += a.x * b.x + a.y * b.y + a.z * b.z + a.w * b.w;
        s2 += a.x * d.x + a.y * d.y + a.z * d.z + a.w * d.w;
    }
    for (int off = 32; off; off >>= 1) {
        s1 += __shfl_xor(s1, off, 64);
        s2 += __shfl_xor(s2, off, 64);
    }
    if (lane == 0) {
        float ap0 = sqrtf(fmaxf(sq[i] + sq[rp]     - 2.f * s1, 1e-12f));
        float apC = sqrtf(fmaxf(sq[i] + sq[rp_new] - 2.f * s2, 1e-12f));
        float apB = (ap0 + an0) * 0.5f;
        float anC = (ap0 + an0) * 0.5f;
        bool useB = p_pos && !p_neg && is_FN;
        bool useC = (!p_pos && p_neg) || (!p_pos && !p_neg && !is_FN);
        bool inverse = !p_pos && !p_neg && is_FN;
        float ap = useB ? apB : (useC ? apC : ap0);
        float an = useB ? anB : (useC ? anC : an0);
        float pl = inverse ? fmaxf(an - ap + MARGIN_F, 0.f)
                           : fmaxf(ap - an + MARGIN_F, 0.f);
        bool conf = prob[i] >= thr;
        row_loss[i] = conf ? pl : 0.f;
        row_corr[i] = (conf && (an >= ap)) ? 1 : 0;
    }
}

// ---------- kernel 6: final reduction ----------
__global__ void reduce_kernel(const float* __restrict__ row_loss, const int* __restrict__ row_corr,
                              const float* __restrict__ prob, const float* __restrict__ thr_p,
                              float* __restrict__ out) {
    __shared__ float sl[256];
    __shared__ int   sc[256];
    __shared__ int   sn[256];
    float thr = *thr_p;
    int tid = threadIdx.x;
    float l = 0.f; int corr = 0, cnt = 0;
    for (int i = tid; i < NROWS; i += 256) {
        l += row_loss[i];
        corr += row_corr[i];
        cnt += (prob[i] >= thr) ? 1 : 0;
    }
    sl[tid] = l; sc[tid] = corr; sn[tid] = cnt;
    __syncthreads();
    for (int off = 128; off; off >>= 1) {
        if (tid < off) {
            sl[tid] += sl[tid + off];
            sc[tid] += sc[tid + off];
            sn[tid] += sn[tid + off];
        }
        __syncthreads();
    }
    if (tid == 0) {
        int cn = sn[0];
        float loss = (cn > 0) ? (sl[0] / (float)(cn > 1 ? cn : 1)) : 0.f;
        out[0] = loss;
        out[1] = (float)sc[0];
        out[2] = (float)cn;
    }
}

extern "C" void kernel_launch(void* const* d_in, const int* in_sizes, int n_in,
                              void* d_out, int out_size, void* d_ws, size_t ws_size,
                              hipStream_t stream) {
    const float* X    = (const float*)d_in[0];
    const float* P    = (const float*)d_in[1];
    const int*   tgt  = (const int*)d_in[2];
    const float* prob = (const float*)d_in[4];
    const float* thr  = (const float*)d_in[5];
    float* out = (float*)d_out;

    char* w = (char*)d_ws;
    auto alloc = [&](size_t bytes) {
        char* p = w;
        w += (bytes + 255) & ~(size_t)255;
        return p;
    };
    float* sq        = (float*)alloc(NROWS * sizeof(float));
    int*   pred_cls  = (int*)  alloc(NROWS * sizeof(int));
    int*   class_cnt = (int*)  alloc(CNUM * sizeof(int));
    int*   class_mem = (int*)  alloc((size_t)CNUM * MAXM * sizeof(int));
    float* top_v     = (float*)alloc((size_t)NROWS * TOPK * sizeof(float));
    int*   top_i     = (int*)  alloc((size_t)NROWS * TOPK * sizeof(int));
    float* row_loss  = (float*)alloc(NROWS * sizeof(float));
    int*   row_corr  = (int*)  alloc(NROWS * sizeof(int));
    char*  var_base  = w;

    // fast-path extra requirement: Xh (16.78 MB) + dist (64 MB)
    size_t fast_need = (size_t)NROWS * DIM * 2 + (size_t)NROWS * NROWS * 4 + (1 << 20);
    bool fast = ((size_t)(var_base - (char*)d_ws) + fast_need) <= ws_size;

    rowsq_kernel<<<NROWS / 4, 256, 0, stream>>>(X, sq);
    predcls_kernel<<<NROWS / 4, 256, 0, stream>>>(P, pred_cls);
    classlist_kernel<<<CNUM / 4, 256, 0, stream>>>(tgt, class_cnt, class_mem);

    if (fast) {
        _Float16* Xh   = (_Float16*)alloc((size_t)NROWS * DIM * 2);
        float*    dist = (float*)alloc((size_t)NROWS * NROWS * 4);
        convert_kernel<<<(NROWS * DIM / 4) / 256, 256, 0, stream>>>(X, Xh);
        mfma_dist_kernel<<<528, 256, 0, stream>>>(Xh, sq, tgt, dist);
        topk_kernel<<<NROWS / 4, 256, 0, stream>>>(dist, top_v, top_i);
    } else {
        float* part_v = (float*)alloc((size_t)NROWS * SLICES * TOPK * sizeof(float));
        int*   part_i = (int*)  alloc((size_t)NROWS * SLICES * TOPK * sizeof(int));
        dist_topk_kernel<<<dim3(NROWS / BM, SLICES), 256, 0, stream>>>(X, sq, tgt, part_v, part_i);
        topk_merge_kernel<<<NROWS / 256, 256, 0, stream>>>(part_v, part_i, top_v, top_i);
    }

    rowlogic_kernel<<<NROWS / 4, 256, 0, stream>>>(X, sq, prob, thr, tgt, pred_cls,
                                                   class_cnt, class_mem, top_v, top_i,
                                                   row_loss, row_corr);
    reduce_kernel<<<1, 256, 0, stream>>>(row_loss, row_corr, prob, thr, out);
}

// Round 4
// 258.058 us; speedup vs baseline: 7.4267x; 1.4214x over previous
//
#include <hip/hip_runtime.h>
#include <hip/hip_bf16.h>
#include <cstdint>
#include <cmath>

#define NROWS 4096
#define DIM   2048
#define CNUM  128
#define MARGIN_F 0.3f
#define TOPK 12
#define MAXM 256
#define GBK 32          // K-tile (f16 elements)
#define CAP 160         // candidate buffer per wave (expected ~35 under pivot)

// fallback-path tiling
#define BM 64
#define BN 64
#define BK 16
#define SLICES 8
#define COLS_PER_SLICE (NROWS / SLICES)

typedef _Float16 f16x8 __attribute__((ext_vector_type(8)));
typedef float    f32x4 __attribute__((ext_vector_type(4)));

// async global->LDS, 16 B per lane; lds dest = wave-uniform base + lane*16
#define GLD_LDS16(g, l)                                                        \
    __builtin_amdgcn_global_load_lds(                                          \
        (const __attribute__((address_space(1))) uint32_t*)(g),                \
        (__attribute__((address_space(3))) uint32_t*)(l), 16, 0, 0)

__device__ __forceinline__ uint32_t rnd_u32(uint32_t row, uint32_t k) {
    uint64_t x = ((uint64_t)row << 32) ^ (0x9E3779B97F4A7C15ULL * (uint64_t)(k + 1u));
    x ^= x >> 33; x *= 0xff51afd7ed558ccdULL;
    x ^= x >> 33; x *= 0xc4ceb9fe1a85ec53ULL;
    x ^= x >> 33;
    return (uint32_t)x;
}

// ---------- kernel 1a: row sum of squares (one wave per row) ----------
__global__ void rowsq_kernel(const float* __restrict__ X, float* __restrict__ sq) {
    int wave = (blockIdx.x * blockDim.x + threadIdx.x) >> 6;
    int lane = threadIdx.x & 63;
    if (wave >= NROWS) return;
    const float4* xp = (const float4*)(X + (size_t)wave * DIM);
    float s = 0.f;
    for (int k = lane; k < DIM / 4; k += 64) {
        float4 v = xp[k];
        s += v.x * v.x + v.y * v.y + v.z * v.z + v.w * v.w;
    }
    for (int off = 32; off; off >>= 1) s += __shfl_xor(s, off, 64);
    if (lane == 0) sq[wave] = s;
}

// ---------- kernel 1b: pred_cls = argmax over C=128 (one wave per row) ----------
__global__ void predcls_kernel(const float* __restrict__ P, int* __restrict__ cls) {
    int row = (blockIdx.x * blockDim.x + threadIdx.x) >> 6;
    int lane = threadIdx.x & 63;
    if (row >= NROWS) return;
    const float* p = P + (size_t)row * CNUM;
    float v0 = p[lane]; int i0 = lane;
    float v1 = p[lane + 64];
    if (v1 > v0) { v0 = v1; i0 = lane + 64; }
    for (int off = 1; off < 64; off <<= 1) {
        float ov = __shfl_xor(v0, off, 64);
        int   oi = __shfl_xor(i0, off, 64);
        if (ov > v0 || (ov == v0 && oi < i0)) { v0 = ov; i0 = oi; }
    }
    if (lane == 0) cls[row] = i0;
}

// ---------- kernel 2: per-class member lists via wave ballot compaction ----------
__global__ void classlist_kernel(const int* __restrict__ tgt,
                                 int* __restrict__ cnt, int* __restrict__ members) {
    int c = (blockIdx.x * blockDim.x + threadIdx.x) >> 6;
    int lane = threadIdx.x & 63;
    if (c >= CNUM) return;
    int k = 0;
    for (int base = 0; base < NROWS; base += 64) {
        int i = base + lane;
        bool m = (tgt[i] == c);
        unsigned long long mask = __ballot(m);
        if (m) {
            int pos = k + __popcll(mask & ((1ull << lane) - 1ull));
            if (pos < MAXM) members[c * MAXM + pos] = i;
        }
        k += __popcll(mask);
    }
    if (lane == 0) cnt[c] = (k < MAXM) ? k : MAXM;
}

// ---------- fast path: fp32 -> f16 convert ----------
__global__ void convert_kernel(const float* __restrict__ X, _Float16* __restrict__ Xh) {
    int idx = blockIdx.x * blockDim.x + threadIdx.x;   // one float4 per thread
    float4 v = ((const float4*)X)[idx];
    _Float16 h[4] = { (_Float16)v.x, (_Float16)v.y, (_Float16)v.z, (_Float16)v.w };
    ((uint2*)Xh)[idx] = *(uint2*)h;
}

// ---------- fast path: m97-style f16 MFMA Gram -> masked squared-distance ----------
__launch_bounds__(256)
__global__ void mfma_dist_kernel(const _Float16* __restrict__ Xh,
                                 const float* __restrict__ sq, const int* __restrict__ tgt,
                                 float* __restrict__ dist) {
    __shared__ _Float16 Ah[128 * GBK];   // row-major [128][32]
    __shared__ _Float16 Bh[128 * GBK];
    __shared__ float    trb[4][16 * 17]; // per-wave transpose buffer
    __shared__ float    sqA[128], sqB[128];
    __shared__ int      tgA[128], tgB[128];

    int b = blockIdx.x;
    int br = 0, S = 0;
    while (b >= S + (32 - br)) { S += 32 - br; br++; }
    int bc = br + (b - S);

    int r0 = br * 128, c0 = bc * 128;
    int tid = threadIdx.x;
    int wave = tid >> 6, lane = tid & 63;
    int wr = wave >> 1, wc = wave & 1;

    if (tid < 128) { sqA[tid] = sq[r0 + tid]; tgA[tid] = tgt[r0 + tid]; }
    else { int t = tid - 128; sqB[t] = sq[c0 + t]; tgB[t] = tgt[c0 + t]; }

    f32x4 acc[4][4];
#pragma unroll
    for (int i = 0; i < 4; i++)
#pragma unroll
        for (int j = 0; j < 4; j++) acc[i][j] = (f32x4)0.f;

    int sr = lane >> 2;            // 0..15 row within slot
    int sc = (lane & 3) * 8;       // 0,8,16,24 col
    const _Float16* gA0 = Xh + (size_t)(r0 + wave * 16 + sr) * DIM + sc;
    const _Float16* gA1 = Xh + (size_t)(r0 + (wave + 4) * 16 + sr) * DIM + sc;
    const _Float16* gB0 = Xh + (size_t)(c0 + wave * 16 + sr) * DIM + sc;
    const _Float16* gB1 = Xh + (size_t)(c0 + (wave + 4) * 16 + sr) * DIM + sc;
    _Float16* lA0 = &Ah[(wave)     * 16 * GBK];
    _Float16* lA1 = &Ah[(wave + 4) * 16 * GBK];
    _Float16* lB0 = &Bh[(wave)     * 16 * GBK];
    _Float16* lB1 = &Bh[(wave + 4) * 16 * GBK];

    int fr = lane & 15, fq = lane >> 4;
    const int fk = fq * 8;

    for (int kb = 0; kb < DIM; kb += GBK) {
        __syncthreads();
        GLD_LDS16(gA0 + kb, lA0);
        GLD_LDS16(gA1 + kb, lA1);
        GLD_LDS16(gB0 + kb, lB0);
        GLD_LDS16(gB1 + kb, lB1);
        __syncthreads();

        f16x8 af[4], bfr[4];
#pragma unroll
        for (int i = 0; i < 4; i++)
            af[i] = *(const f16x8*)&Ah[(wr * 64 + i * 16 + fr) * GBK + fk];
#pragma unroll
        for (int j = 0; j < 4; j++)
            bfr[j] = *(const f16x8*)&Bh[(wc * 64 + j * 16 + fr) * GBK + fk];
#pragma unroll
        for (int i = 0; i < 4; i++)
#pragma unroll
            for (int j = 0; j < 4; j++)
                acc[i][j] = __builtin_amdgcn_mfma_f32_16x16x32_f16(af[i], bfr[j], acc[i][j], 0, 0, 0);
    }

    float* tb = trb[wave];
#pragma unroll
    for (int i = 0; i < 4; i++) {
#pragma unroll
        for (int j = 0; j < 4; j++) {
            int lcol = wc * 64 + j * 16 + fr;
            float d[4];
#pragma unroll
            for (int r = 0; r < 4; r++) {
                int lrow = wr * 64 + i * 16 + fq * 4 + r;
                float v = sqA[lrow] + sqB[lcol] - 2.f * acc[i][j][r];
                if (tgA[lrow] == tgB[lcol]) v = INFINITY;
                d[r] = v;
                dist[(size_t)(r0 + lrow) * NROWS + (c0 + lcol)] = v;
            }
            if (br != bc) {
#pragma unroll
                for (int r = 0; r < 4; r++) tb[fr * 17 + fq * 4 + r] = d[r];
#pragma unroll
                for (int r = 0; r < 4; r++) {
                    float v = tb[(fq * 4 + r) * 17 + fr];
                    int grow = c0 + wc * 64 + j * 16 + fq * 4 + r;
                    int gcol = r0 + wr * 64 + i * 16 + fr;
                    dist[(size_t)grow * NROWS + gcol] = v;
                }
            }
        }
    }
}

// ---------- fast path: per-row top-12 via pivot filter + ballot compaction ----------
// One wave per row. Values live in registers (64/lane); τ found by interpolated
// bisection so that 12 <= count(v<τ) <= CAP; candidates compacted to LDS;
// exact top-12 by 12 rounds of wave argmin with (value, index) tiebreak.
__launch_bounds__(256)
__global__ void topk_kernel(const float* __restrict__ dist,
                            float* __restrict__ top_v, int* __restrict__ top_i) {
    __shared__ float cbv[4][CAP];
    __shared__ int   cbi[4][CAP];
    int wave = threadIdx.x >> 6, lane = threadIdx.x & 63;
    int row = blockIdx.x * 4 + wave;
    const float4* d = (const float4*)(dist + (size_t)row * NROWS);

    // load the whole row: 16 float4 per lane (element idx = (t*64+lane)*4 + c)
    float4 v[16];
#pragma unroll
    for (int t = 0; t < 16; t++) v[t] = d[t * 64 + lane];

    // finite min / max / mean
    float lmin = INFINITY, lmax = -INFINITY, lsum = 0.f;
    int lcnt = 0;
#pragma unroll
    for (int t = 0; t < 16; t++) {
        float xs[4] = { v[t].x, v[t].y, v[t].z, v[t].w };
#pragma unroll
        for (int c = 0; c < 4; c++) {
            float x = xs[c];
            bool fin = x < INFINITY;
            lmin = fminf(lmin, x);
            lmax = fmaxf(lmax, fin ? x : -INFINITY);
            lsum += fin ? x : 0.f;
            lcnt += fin ? 1 : 0;
        }
    }
    for (int off = 32; off; off >>= 1) {
        lmin = fminf(lmin, __shfl_xor(lmin, off, 64));
        lmax = fmaxf(lmax, __shfl_xor(lmax, off, 64));
        lsum += __shfl_xor(lsum, off, 64);
        lcnt += __shfl_xor(lcnt, off, 64);
    }
    float mu = lsum / (float)(lcnt > 0 ? lcnt : 1);

    // pivot search: interpolated guess, then bisection on [lmin, lmax+1]
    float lo = lmin, hi = lmax + 1.0f;
    float tau = lmin + 0.3f * (mu - lmin);
    if (!(tau > lo && tau < hi)) tau = 0.5f * (lo + hi);
    for (int it = 0; it < 32; it++) {
        int lc = 0;
#pragma unroll
        for (int t = 0; t < 16; t++) {
            lc += (v[t].x < tau) + (v[t].y < tau) + (v[t].z < tau) + (v[t].w < tau);
        }
        for (int off = 32; off; off >>= 1) lc += __shfl_xor(lc, off, 64);
        if (lc >= TOPK && lc <= CAP) break;
        if (lc < TOPK) lo = tau; else hi = tau;
        tau = 0.5f * (lo + hi);
    }

    // ballot-compact candidates (v < tau) into LDS, preserving index order
    int cnt = 0;
#pragma unroll
    for (int t = 0; t < 16; t++) {
        float xs[4] = { v[t].x, v[t].y, v[t].z, v[t].w };
#pragma unroll
        for (int c = 0; c < 4; c++) {
            float x = xs[c];
            bool p = x < tau;
            unsigned long long mk = __ballot(p);
            if (p) {
                int pos = cnt + __popcll(mk & ((1ull << lane) - 1ull));
                if (pos < CAP) {
                    cbv[wave][pos] = x;
                    cbi[wave][pos] = (t * 64 + lane) * 4 + c;
                }
            }
            cnt += __popcll(mk);
        }
    }
    if (cnt > CAP) cnt = CAP;

    // each lane holds up to 3 candidates in registers
    float mv[3]; int mi[3];
#pragma unroll
    for (int r = 0; r < 3; r++) {
        int p = r * 64 + lane;
        bool ok = p < cnt;
        mv[r] = ok ? cbv[wave][p] : INFINITY;
        mi[r] = ok ? cbi[wave][p] : 0x7FFFFFFF;
    }

    // 12 rounds of wave argmin with (value, index) lexicographic order
    for (int t = 0; t < TOPK; t++) {
        float bv = mv[0]; int bi = mi[0];
        if (mv[1] < bv || (mv[1] == bv && mi[1] < bi)) { bv = mv[1]; bi = mi[1]; }
        if (mv[2] < bv || (mv[2] == bv && mi[2] < bi)) { bv = mv[2]; bi = mi[2]; }
        for (int off = 32; off; off >>= 1) {
            float ov = __shfl_xor(bv, off, 64);
            int   oi = __shfl_xor(bi, off, 64);
            if (ov < bv || (ov == bv && oi < bi)) { bv = ov; bi = oi; }
        }
        if (lane == 0) {
            top_v[(size_t)row * TOPK + t] = bv;
            int si = (bi >= 0 && bi < NROWS) ? bi : 0;   // safety clamp
            top_i[(size_t)row * TOPK + t] = si;
        }
        // remove winner from all lanes (butterfly left bv/bi identical everywhere)
#pragma unroll
        for (int r = 0; r < 3; r++)
            if (mi[r] == bi) { mv[r] = INFINITY; mi[r] = 0x7FFFFFFF; }
    }
}

// ---------- fallback path (proven R1): fused fp32 GEMM + per-row top-12 ----------
__launch_bounds__(256)
__global__ void dist_topk_kernel(const float* __restrict__ X, const float* __restrict__ sq,
                                 const int* __restrict__ tgt,
                                 float* __restrict__ part_v, int* __restrict__ part_i) {
    __shared__ float As[BK][BM];
    __shared__ float Bs[BK][BN];
    __shared__ float Cs[BM][BN + 1];
    __shared__ float sqA[BM], sqB[BN];
    __shared__ int   tgA[BM], tgB[BN];

    int rowBase = blockIdx.x * BM;
    int slice = blockIdx.y;
    int tid = threadIdx.x;
    int tx = tid & 15, ty = tid >> 4;

    if (tid < BM) { sqA[tid] = sq[rowBase + tid]; tgA[tid] = tgt[rowBase + tid]; }

    float lv[TOPK]; int li[TOPK];
#pragma unroll
    for (int k = 0; k < TOPK; k++) { lv[k] = INFINITY; li[k] = -1; }

    for (int jt = 0; jt < COLS_PER_SLICE / BN; jt++) {
        int colBase = slice * COLS_PER_SLICE + jt * BN;
        __syncthreads();
        if (tid < BN) { sqB[tid] = sq[colBase + tid]; tgB[tid] = tgt[colBase + tid]; }

        float acc[4][4] = {};
        for (int kb = 0; kb < DIM; kb += BK) {
            int r  = tid >> 2;
            int kk = (tid & 3) * 4;
            float4 va = *(const float4*)(X + (size_t)(rowBase + r) * DIM + kb + kk);
            As[kk + 0][r] = va.x; As[kk + 1][r] = va.y; As[kk + 2][r] = va.z; As[kk + 3][r] = va.w;
            float4 vb = *(const float4*)(X + (size_t)(colBase + r) * DIM + kb + kk);
            Bs[kk + 0][r] = vb.x; Bs[kk + 1][r] = vb.y; Bs[kk + 2][r] = vb.z; Bs[kk + 3][r] = vb.w;
            __syncthreads();
#pragma unroll
            for (int k = 0; k < BK; k++) {
                float a[4], b[4];
                *(float4*)a = *(const float4*)&As[k][ty * 4];
                *(float4*)b = *(const float4*)&Bs[k][tx * 4];
#pragma unroll
                for (int i2 = 0; i2 < 4; i2++)
#pragma unroll
                    for (int j2 = 0; j2 < 4; j2++)
                        acc[i2][j2] += a[i2] * b[j2];
            }
            __syncthreads();
        }
#pragma unroll
        for (int i2 = 0; i2 < 4; i2++) {
            int r = ty * 4 + i2;
#pragma unroll
            for (int j2 = 0; j2 < 4; j2++) {
                int c = tx * 4 + j2;
                float d2 = sqA[r] + sqB[c] - 2.f * acc[i2][j2];
                if (tgA[r] == tgB[c]) d2 = INFINITY;
                Cs[r][c] = d2;
            }
        }
        __syncthreads();
        if (tid < BM) {
            int r = tid;
            for (int c = 0; c < BN; c++) {
                float v = Cs[r][c];
                if (v < lv[TOPK - 1]) {
                    float nv = v; int ni = colBase + c;
#pragma unroll
                    for (int p = 0; p < TOPK; p++) {
                        if (nv < lv[p]) {
                            float tv = lv[p]; int ti = li[p];
                            lv[p] = nv; li[p] = ni;
                            nv = tv; ni = ti;
                        }
                    }
                }
            }
        }
    }
    if (tid < BM) {
        int r = tid;
#pragma unroll
        for (int k = 0; k < TOPK; k++) {
            size_t o = ((size_t)(rowBase + r) * SLICES + slice) * TOPK + k;
            part_v[o] = lv[k];
            part_i[o] = li[k];
        }
    }
}

__global__ void topk_merge_kernel(const float* __restrict__ part_v, const int* __restrict__ part_i,
                                  float* __restrict__ top_v, int* __restrict__ top_i) {
    int row = blockIdx.x * blockDim.x + threadIdx.x;
    if (row >= NROWS) return;
    float lv[TOPK]; int li[TOPK];
#pragma unroll
    for (int k = 0; k < TOPK; k++) { lv[k] = INFINITY; li[k] = -1; }
    for (int s = 0; s < SLICES; s++) {
        for (int k = 0; k < TOPK; k++) {
            size_t o = ((size_t)row * SLICES + s) * TOPK + k;
            float v = part_v[o];
            if (!(v < lv[TOPK - 1])) break;
            int idx = part_i[o];
            float nv = v; int ni = idx;
#pragma unroll
            for (int p = 0; p < TOPK; p++) {
                if (nv < lv[p]) {
                    float tv = lv[p]; int ti = li[p];
                    lv[p] = nv; li[p] = ni;
                    nv = tv; ni = ti;
                }
            }
        }
    }
#pragma unroll
    for (int k = 0; k < TOPK; k++) {
        top_v[(size_t)row * TOPK + k] = lv[k];
        top_i[(size_t)row * TOPK + k] = li[k];
    }
}

// ---------- kernel 5: per-row triplet logic (one wave per row) ----------
__global__ void rowlogic_kernel(const float* __restrict__ X, const float* __restrict__ sq,
                                const float* __restrict__ prob, const float* __restrict__ thr_p,
                                const int* __restrict__ tgt, const int* __restrict__ pred_cls,
                                const int* __restrict__ class_cnt, const int* __restrict__ class_mem,
                                const float* __restrict__ top_v, const int* __restrict__ top_i,
                                float* __restrict__ row_loss, int* __restrict__ row_corr) {
    int i = (blockIdx.x * blockDim.x + threadIdx.x) >> 6;
    int lane = threadIdx.x & 63;
    if (i >= NROWS) return;
    float thr = *thr_p;

    int c = tgt[i];
    int cc = class_cnt[c];
    const int* mem = class_mem + c * MAXM;

    int pos_i = 0;
    for (int k = 0; k < cc; k++) { if (mem[k] == i) { pos_i = k; break; } }

    int rp = 0;
    if (cc > 1) {
        uint32_t r = rnd_u32((uint32_t)i, 0x9111u) % (uint32_t)(cc - 1);
        if ((int)r >= pos_i) r++;
        rp = mem[r];
    }

    int hn = top_i[(size_t)i * TOPK + 0];
    float an0 = sqrtf(fmaxf(top_v[(size_t)i * TOPK + 0], 1e-12f));
    bool p_neg = prob[hn] >= thr;
    bool is_FN = (pred_cls[hn] == c);

    int sel = 11;
    for (int k = 1; k <= 11; k++) {
        int cd = top_i[(size_t)i * TOPK + k];
        if (prob[cd] >= thr) { sel = k; break; }
    }
    float anB = sqrtf(fmaxf(top_v[(size_t)i * TOPK + sel], 1e-12f));

    int first_valid = -1, last_draw = 0;
    for (int k = 0; k < 6; k++) {
        uint32_t r = rnd_u32((uint32_t)i, 0xD000u + (uint32_t)k) % (uint32_t)(cc > 0 ? cc : 1);
        int dk = mem[r];
        last_draw = dk;
        if (first_valid < 0 && dk != i && prob[dk] >= thr) first_valid = dk;
    }
    int rp_new = (first_valid >= 0) ? first_valid : last_draw;
    bool p_pos = prob[rp] >= thr;

    const float4* xi = (const float4*)(X + (size_t)i * DIM);
    const float4* xr = (const float4*)(X + (size_t)rp * DIM);
    const float4* xn = (const float4*)(X + (size_t)rp_new * DIM);
    float s1 = 0.f, s2 = 0.f;
    for (int k = lane; k < DIM / 4; k += 64) {
        float4 a = xi[k], b = xr[k], d = xn[k];
        s1 += a.x * b.x + a.y * b.y + a.z * b.z + a.w * b.w;
        s2 += a.x * d.x + a.y * d.y + a.z * d.z + a.w * d.w;
    }
    for (int off = 32; off; off >>= 1) {
        s1 += __shfl_xor(s1, off, 64);
        s2 += __shfl_xor(s2, off, 64);
    }
    if (lane == 0) {
        float ap0 = sqrtf(fmaxf(sq[i] + sq[rp]     - 2.f * s1, 1e-12f));
        float apC = sqrtf(fmaxf(sq[i] + sq[rp_new] - 2.f * s2, 1e-12f));
        float apB = (ap0 + an0) * 0.5f;
        float anC = (ap0 + an0) * 0.5f;
        bool useB = p_pos && !p_neg && is_FN;
        bool useC = (!p_pos && p_neg) || (!p_pos && !p_neg && !is_FN);
        bool inverse = !p_pos && !p_neg && is_FN;
        float ap = useB ? apB : (useC ? apC : ap0);
        float an = useB ? anB : (useC ? anC : an0);
        float pl = inverse ? fmaxf(an - ap + MARGIN_F, 0.f)
                           : fmaxf(ap - an + MARGIN_F, 0.f);
        bool conf = prob[i] >= thr;
        row_loss[i] = conf ? pl : 0.f;
        row_corr[i] = (conf && (an >= ap)) ? 1 : 0;
    }
}

// ---------- kernel 6: final reduction ----------
__global__ void reduce_kernel(const float* __restrict__ row_loss, const int* __restrict__ row_corr,
                              const float* __restrict__ prob, const float* __restrict__ thr_p,
                              float* __restrict__ out) {
    __shared__ float sl[256];
    __shared__ int   sc[256];
    __shared__ int   sn[256];
    float thr = *thr_p;
    int tid = threadIdx.x;
    float l = 0.f; int corr = 0, cnt = 0;
    for (int i = tid; i < NROWS; i += 256) {
        l += row_loss[i];
        corr += row_corr[i];
        cnt += (prob[i] >= thr) ? 1 : 0;
    }
    sl[tid] = l; sc[tid] = corr; sn[tid] = cnt;
    __syncthreads();
    for (int off = 128; off; off >>= 1) {
        if (tid < off) {
            sl[tid] += sl[tid + off];
            sc[tid] += sc[tid + off];
            sn[tid] += sn[tid + off];
        }
        __syncthreads();
    }
    if (tid == 0) {
        int cn = sn[0];
        float loss = (cn > 0) ? (sl[0] / (float)(cn > 1 ? cn : 1)) : 0.f;
        out[0] = loss;
        out[1] = (float)sc[0];
        out[2] = (float)cn;
    }
}

extern "C" void kernel_launch(void* const* d_in, const int* in_sizes, int n_in,
                              void* d_out, int out_size, void* d_ws, size_t ws_size,
                              hipStream_t stream) {
    const float* X    = (const float*)d_in[0];
    const float* P    = (const float*)d_in[1];
    const int*   tgt  = (const int*)d_in[2];
    const float* prob = (const float*)d_in[4];
    const float* thr  = (const float*)d_in[5];
    float* out = (float*)d_out;

    char* w = (char*)d_ws;
    auto alloc = [&](size_t bytes) {
        char* p = w;
        w += (bytes + 255) & ~(size_t)255;
        return p;
    };
    float* sq        = (float*)alloc(NROWS * sizeof(float));
    int*   pred_cls  = (int*)  alloc(NROWS * sizeof(int));
    int*   class_cnt = (int*)  alloc(CNUM * sizeof(int));
    int*   class_mem = (int*)  alloc((size_t)CNUM * MAXM * sizeof(int));
    float* top_v     = (float*)alloc((size_t)NROWS * TOPK * sizeof(float));
    int*   top_i     = (int*)  alloc((size_t)NROWS * TOPK * sizeof(int));
    float* row_loss  = (float*)alloc(NROWS * sizeof(float));
    int*   row_corr  = (int*)  alloc(NROWS * sizeof(int));
    char*  var_base  = w;

    size_t fast_need = (size_t)NROWS * DIM * 2 + (size_t)NROWS * NROWS * 4 + (1 << 20);
    bool fast = ((size_t)(var_base - (char*)d_ws) + fast_need) <= ws_size;

    rowsq_kernel<<<NROWS / 4, 256, 0, stream>>>(X, sq);
    predcls_kernel<<<NROWS / 4, 256, 0, stream>>>(P, pred_cls);
    classlist_kernel<<<CNUM / 4, 256, 0, stream>>>(tgt, class_cnt, class_mem);

    if (fast) {
        _Float16* Xh   = (_Float16*)alloc((size_t)NROWS * DIM * 2);
        float*    dist = (float*)alloc((size_t)NROWS * NROWS * 4);
        convert_kernel<<<(NROWS * DIM / 4) / 256, 256, 0, stream>>>(X, Xh);
        mfma_dist_kernel<<<528, 256, 0, stream>>>(Xh, sq, tgt, dist);
        topk_kernel<<<NROWS / 4, 256, 0, stream>>>(dist, top_v, top_i);
    } else {
        float* part_v = (float*)alloc((size_t)NROWS * SLICES * TOPK * sizeof(float));
        int*   part_i = (int*)  alloc((size_t)NROWS * SLICES * TOPK * sizeof(int));
        dist_topk_kernel<<<dim3(NROWS / BM, SLICES), 256, 0, stream>>>(X, sq, tgt, part_v, part_i);
        topk_merge_kernel<<<NROWS / 256, 256, 0, stream>>>(part_v, part_i, top_v, top_i);
    }

    rowlogic_kernel<<<NROWS / 4, 256, 0, stream>>>(X, sq, prob, thr, tgt, pred_cls,
                                                   class_cnt, class_mem, top_v, top_i,
                                                   row_loss, row_corr);
    reduce_kernel<<<1, 256, 0, stream>>>(row_loss, row_corr, prob, thr, out);
}

// Round 5
// 235.763 us; speedup vs baseline: 8.1290x; 1.0946x over previous
//
#include <hip/hip_runtime.h>
#include <hip/hip_bf16.h>
#include <cstdint>
#include <cmath>

#define NROWS 4096
#define DIM   2048
#define CNUM  128
#define MARGIN_F 0.3f
#define TOPK 12
#define MAXM 256
#define GBK2 64         // K-tile (f16 elements), double-buffered
#define CAP 160         // topk candidate buffer per wave

// fallback-path tiling
#define BM 64
#define BN 64
#define BK 16
#define SLICES 8
#define COLS_PER_SLICE (NROWS / SLICES)

typedef _Float16 f16x8 __attribute__((ext_vector_type(8)));
typedef float    f32x4 __attribute__((ext_vector_type(4)));

// async global->LDS, 16 B per lane; lds dest = wave-uniform base + lane*16
#define GLD_LDS16(g, l)                                                        \
    __builtin_amdgcn_global_load_lds(                                          \
        (const __attribute__((address_space(1))) uint32_t*)(g),                \
        (__attribute__((address_space(3))) uint32_t*)(l), 16, 0, 0)

__device__ __forceinline__ uint32_t rnd_u32(uint32_t row, uint32_t k) {
    uint64_t x = ((uint64_t)row << 32) ^ (0x9E3779B97F4A7C15ULL * (uint64_t)(k + 1u));
    x ^= x >> 33; x *= 0xff51afd7ed558ccdULL;
    x ^= x >> 33; x *= 0xc4ceb9fe1a85ec53ULL;
    x ^= x >> 33;
    return (uint32_t)x;
}

// ---------- kernel 1a: row sum of squares (fallback path) ----------
__global__ void rowsq_kernel(const float* __restrict__ X, float* __restrict__ sq) {
    int wave = (blockIdx.x * blockDim.x + threadIdx.x) >> 6;
    int lane = threadIdx.x & 63;
    if (wave >= NROWS) return;
    const float4* xp = (const float4*)(X + (size_t)wave * DIM);
    float s = 0.f;
    for (int k = lane; k < DIM / 4; k += 64) {
        float4 v = xp[k];
        s += v.x * v.x + v.y * v.y + v.z * v.z + v.w * v.w;
    }
    for (int off = 32; off; off >>= 1) s += __shfl_xor(s, off, 64);
    if (lane == 0) sq[wave] = s;
}

// ---------- fast path: fused fp32->f16 convert + row sum of squares ----------
// one block per row; 256 threads x 8 elems
__global__ void prep_kernel(const float* __restrict__ X, _Float16* __restrict__ Xh,
                            float* __restrict__ sq) {
    __shared__ float ws[4];
    int row = blockIdx.x, tid = threadIdx.x;
    int wave = tid >> 6, lane = tid & 63;
    const float4* xp = (const float4*)(X + (size_t)row * DIM);
    float4 a = xp[tid * 2], b = xp[tid * 2 + 1];
    float s = a.x * a.x + a.y * a.y + a.z * a.z + a.w * a.w
            + b.x * b.x + b.y * b.y + b.z * b.z + b.w * b.w;
    _Float16 h[8] = { (_Float16)a.x, (_Float16)a.y, (_Float16)a.z, (_Float16)a.w,
                      (_Float16)b.x, (_Float16)b.y, (_Float16)b.z, (_Float16)b.w };
    ((uint4*)(Xh + (size_t)row * DIM))[tid] = *(uint4*)h;
    for (int off = 32; off; off >>= 1) s += __shfl_xor(s, off, 64);
    if (lane == 0) ws[wave] = s;
    __syncthreads();
    if (tid == 0) sq[row] = ws[0] + ws[1] + ws[2] + ws[3];
}

// ---------- kernel 1b: pred_cls = argmax over C=128 (one wave per row) ----------
__global__ void predcls_kernel(const float* __restrict__ P, int* __restrict__ cls) {
    int row = (blockIdx.x * blockDim.x + threadIdx.x) >> 6;
    int lane = threadIdx.x & 63;
    if (row >= NROWS) return;
    const float* p = P + (size_t)row * CNUM;
    float v0 = p[lane]; int i0 = lane;
    float v1 = p[lane + 64];
    if (v1 > v0) { v0 = v1; i0 = lane + 64; }
    for (int off = 1; off < 64; off <<= 1) {
        float ov = __shfl_xor(v0, off, 64);
        int   oi = __shfl_xor(i0, off, 64);
        if (ov > v0 || (ov == v0 && oi < i0)) { v0 = ov; i0 = oi; }
    }
    if (lane == 0) cls[row] = i0;
}

// ---------- kernel 2: per-class member lists via wave ballot compaction ----------
__global__ void classlist_kernel(const int* __restrict__ tgt,
                                 int* __restrict__ cnt, int* __restrict__ members) {
    int c = (blockIdx.x * blockDim.x + threadIdx.x) >> 6;
    int lane = threadIdx.x & 63;
    if (c >= CNUM) return;
    int k = 0;
    for (int base = 0; base < NROWS; base += 64) {
        int i = base + lane;
        bool m = (tgt[i] == c);
        unsigned long long mask = __ballot(m);
        if (m) {
            int pos = k + __popcll(mask & ((1ull << lane) - 1ull));
            if (pos < MAXM) members[c * MAXM + pos] = i;
        }
        k += __popcll(mask);
    }
    if (lane == 0) cnt[c] = (k < MAXM) ? k : MAXM;
}

// ---------- fast path: f16 MFMA Gram, BK=64 double-buffered, XOR-swizzled LDS ----
// 528 upper-triangle 128x128 tiles; 4 waves in 2x2 of 64x64; one barrier/iter;
// prefetch into the other buffer issued BEFORE the MFMA block so the barrier's
// vmcnt drain lands after ~32 MFMA of latency-hiding compute.
// LDS bank swizzle: row r's 16B chunk j is stored at slot j^(r&7) (applied on the
// per-lane GLOBAL address, keeping the wave-uniform LDS base law intact).
__launch_bounds__(256, 2)
__global__ void mfma_dist_kernel(const _Float16* __restrict__ Xh,
                                 const float* __restrict__ sq, const int* __restrict__ tgt,
                                 float* __restrict__ dist) {
    __shared__ _Float16 Ah[2][128 * GBK2];   // 2 x 16 KB
    __shared__ _Float16 Bh[2][128 * GBK2];   // 2 x 16 KB
    __shared__ float    trb[4][16 * 17];
    __shared__ float    sqA[128], sqB[128];
    __shared__ int      tgA[128], tgB[128];

    int b = blockIdx.x;
    int br = 0, S = 0;
    while (b >= S + (32 - br)) { S += 32 - br; br++; }
    int bc = br + (b - S);

    int r0 = br * 128, c0 = bc * 128;
    int tid = threadIdx.x;
    int wave = tid >> 6, lane = tid & 63;
    int wr = wave >> 1, wc = wave & 1;

    if (tid < 128) { sqA[tid] = sq[r0 + tid]; tgA[tid] = tgt[r0 + tid]; }
    else { int t = tid - 128; sqB[t] = sq[c0 + t]; tgB[t] = tgt[c0 + t]; }

    f32x4 acc[4][4];
#pragma unroll
    for (int i = 0; i < 4; i++)
#pragma unroll
        for (int j = 0; j < 4; j++) acc[i][j] = (f32x4)0.f;

    // staging: per wave 4 A-issues + 4 B-issues, 8 rows (1 KB) each
    const _Float16* gA[4]; const _Float16* gB[4];
    int ldsOff[4];
#pragma unroll
    for (int q = 0; q < 4; q++) {
        int r = wave * 32 + q * 8 + (lane >> 3);      // row within 128-tile
        int j = (lane & 7) ^ (r & 7);                 // swizzled source chunk
        gA[q] = Xh + (size_t)(r0 + r) * DIM + j * 8;
        gB[q] = Xh + (size_t)(c0 + r) * DIM + j * 8;
        ldsOff[q] = (wave * 32 + q * 8) * GBK2;       // wave-uniform
    }

    auto stage = [&](int buf, int kOff) {
#pragma unroll
        for (int q = 0; q < 4; q++) {
            GLD_LDS16(gA[q] + kOff, &Ah[buf][ldsOff[q]]);
            GLD_LDS16(gB[q] + kOff, &Bh[buf][ldsOff[q]]);
        }
    };

    stage(0, 0);
    int fr = lane & 15, fq = lane >> 4;

    for (int it = 0; it < DIM / GBK2; it++) {         // 32 iterations
        int cur = it & 1;
        __syncthreads();                              // drains prev prefetch; guards buffer reuse
        if (it + 1 < DIM / GBK2) stage(cur ^ 1, (it + 1) * GBK2);
#pragma unroll
        for (int s = 0; s < 2; s++) {
            f16x8 af[4], bf[4];
#pragma unroll
            for (int i = 0; i < 4; i++) {
                int row = wr * 64 + i * 16 + fr;
                int jj = (s * 4 + fq) ^ (row & 7);
                af[i] = *(const f16x8*)&Ah[cur][row * GBK2 + jj * 8];
            }
#pragma unroll
            for (int j = 0; j < 4; j++) {
                int col = wc * 64 + j * 16 + fr;
                int jj = (s * 4 + fq) ^ (col & 7);
                bf[j] = *(const f16x8*)&Bh[cur][col * GBK2 + jj * 8];
            }
#pragma unroll
            for (int i = 0; i < 4; i++)
#pragma unroll
                for (int j = 0; j < 4; j++)
                    acc[i][j] = __builtin_amdgcn_mfma_f32_16x16x32_f16(af[i], bf[j], acc[i][j], 0, 0, 0);
        }
    }

    // epilogue: d2 = sqA+sqB-2*dot, mask positives; direct + LDS-transposed mirror
    float* tb = trb[wave];
#pragma unroll
    for (int i = 0; i < 4; i++) {
#pragma unroll
        for (int j = 0; j < 4; j++) {
            int lcol = wc * 64 + j * 16 + fr;
            float d[4];
#pragma unroll
            for (int r = 0; r < 4; r++) {
                int lrow = wr * 64 + i * 16 + fq * 4 + r;
                float v = sqA[lrow] + sqB[lcol] - 2.f * acc[i][j][r];
                if (tgA[lrow] == tgB[lcol]) v = INFINITY;
                d[r] = v;
                dist[(size_t)(r0 + lrow) * NROWS + (c0 + lcol)] = v;
            }
            if (br != bc) {
#pragma unroll
                for (int r = 0; r < 4; r++) tb[fr * 17 + fq * 4 + r] = d[r];
#pragma unroll
                for (int r = 0; r < 4; r++) {
                    float v = tb[(fq * 4 + r) * 17 + fr];
                    int grow = c0 + wc * 64 + j * 16 + fq * 4 + r;
                    int gcol = r0 + wr * 64 + i * 16 + fr;
                    dist[(size_t)grow * NROWS + gcol] = v;
                }
            }
        }
    }
}

// ---------- fast path: per-row top-12 via pivot filter + ballot compaction ----------
__launch_bounds__(256)
__global__ void topk_kernel(const float* __restrict__ dist,
                            float* __restrict__ top_v, int* __restrict__ top_i) {
    __shared__ float cbv[4][CAP];
    __shared__ int   cbi[4][CAP];
    int wave = threadIdx.x >> 6, lane = threadIdx.x & 63;
    int row = blockIdx.x * 4 + wave;
    const float4* d = (const float4*)(dist + (size_t)row * NROWS);

    float4 v[16];
#pragma unroll
    for (int t = 0; t < 16; t++) v[t] = d[t * 64 + lane];

    float lmin = INFINITY, lmax = -INFINITY, lsum = 0.f;
    int lcnt = 0;
#pragma unroll
    for (int t = 0; t < 16; t++) {
        float xs[4] = { v[t].x, v[t].y, v[t].z, v[t].w };
#pragma unroll
        for (int c = 0; c < 4; c++) {
            float x = xs[c];
            bool fin = x < INFINITY;
            lmin = fminf(lmin, x);
            lmax = fmaxf(lmax, fin ? x : -INFINITY);
            lsum += fin ? x : 0.f;
            lcnt += fin ? 1 : 0;
        }
    }
    for (int off = 32; off; off >>= 1) {
        lmin = fminf(lmin, __shfl_xor(lmin, off, 64));
        lmax = fmaxf(lmax, __shfl_xor(lmax, off, 64));
        lsum += __shfl_xor(lsum, off, 64);
        lcnt += __shfl_xor(lcnt, off, 64);
    }
    float mu = lsum / (float)(lcnt > 0 ? lcnt : 1);

    float lo = lmin, hi = lmax + 1.0f;
    float tau = lmin + 0.3f * (mu - lmin);
    if (!(tau > lo && tau < hi)) tau = 0.5f * (lo + hi);
    for (int it = 0; it < 32; it++) {
        int lc = 0;
#pragma unroll
        for (int t = 0; t < 16; t++) {
            lc += (v[t].x < tau) + (v[t].y < tau) + (v[t].z < tau) + (v[t].w < tau);
        }
        for (int off = 32; off; off >>= 1) lc += __shfl_xor(lc, off, 64);
        if (lc >= TOPK && lc <= CAP) break;
        if (lc < TOPK) lo = tau; else hi = tau;
        tau = 0.5f * (lo + hi);
    }

    int cnt = 0;
#pragma unroll
    for (int t = 0; t < 16; t++) {
        float xs[4] = { v[t].x, v[t].y, v[t].z, v[t].w };
#pragma unroll
        for (int c = 0; c < 4; c++) {
            float x = xs[c];
            bool p = x < tau;
            unsigned long long mk = __ballot(p);
            if (p) {
                int pos = cnt + __popcll(mk & ((1ull << lane) - 1ull));
                if (pos < CAP) {
                    cbv[wave][pos] = x;
                    cbi[wave][pos] = (t * 64 + lane) * 4 + c;
                }
            }
            cnt += __popcll(mk);
        }
    }
    if (cnt > CAP) cnt = CAP;

    float mv[3]; int mi[3];
#pragma unroll
    for (int r = 0; r < 3; r++) {
        int p = r * 64 + lane;
        bool ok = p < cnt;
        mv[r] = ok ? cbv[wave][p] : INFINITY;
        mi[r] = ok ? cbi[wave][p] : 0x7FFFFFFF;
    }

    for (int t = 0; t < TOPK; t++) {
        float bv = mv[0]; int bi = mi[0];
        if (mv[1] < bv || (mv[1] == bv && mi[1] < bi)) { bv = mv[1]; bi = mi[1]; }
        if (mv[2] < bv || (mv[2] == bv && mi[2] < bi)) { bv = mv[2]; bi = mi[2]; }
        for (int off = 32; off; off >>= 1) {
            float ov = __shfl_xor(bv, off, 64);
            int   oi = __shfl_xor(bi, off, 64);
            if (ov < bv || (ov == bv && oi < bi)) { bv = ov; bi = oi; }
        }
        if (lane == 0) {
            top_v[(size_t)row * TOPK + t] = bv;
            int si = (bi >= 0 && bi < NROWS) ? bi : 0;
            top_i[(size_t)row * TOPK + t] = si;
        }
#pragma unroll
        for (int r = 0; r < 3; r++)
            if (mi[r] == bi) { mv[r] = INFINITY; mi[r] = 0x7FFFFFFF; }
    }
}

// ---------- fallback path (proven R1): fused fp32 GEMM + per-row top-12 ----------
__launch_bounds__(256)
__global__ void dist_topk_kernel(const float* __restrict__ X, const float* __restrict__ sq,
                                 const int* __restrict__ tgt,
                                 float* __restrict__ part_v, int* __restrict__ part_i) {
    __shared__ float As[BK][BM];
    __shared__ float Bs[BK][BN];
    __shared__ float Cs[BM][BN + 1];
    __shared__ float sqA[BM], sqB[BN];
    __shared__ int   tgA[BM], tgB[BN];

    int rowBase = blockIdx.x * BM;
    int slice = blockIdx.y;
    int tid = threadIdx.x;
    int tx = tid & 15, ty = tid >> 4;

    if (tid < BM) { sqA[tid] = sq[rowBase + tid]; tgA[tid] = tgt[rowBase + tid]; }

    float lv[TOPK]; int li[TOPK];
#pragma unroll
    for (int k = 0; k < TOPK; k++) { lv[k] = INFINITY; li[k] = -1; }

    for (int jt = 0; jt < COLS_PER_SLICE / BN; jt++) {
        int colBase = slice * COLS_PER_SLICE + jt * BN;
        __syncthreads();
        if (tid < BN) { sqB[tid] = sq[colBase + tid]; tgB[tid] = tgt[colBase + tid]; }

        float acc[4][4] = {};
        for (int kb = 0; kb < DIM; kb += BK) {
            int r  = tid >> 2;
            int kk = (tid & 3) * 4;
            float4 va = *(const float4*)(X + (size_t)(rowBase + r) * DIM + kb + kk);
            As[kk + 0][r] = va.x; As[kk + 1][r] = va.y; As[kk + 2][r] = va.z; As[kk + 3][r] = va.w;
            float4 vb = *(const float4*)(X + (size_t)(colBase + r) * DIM + kb + kk);
            Bs[kk + 0][r] = vb.x; Bs[kk + 1][r] = vb.y; Bs[kk + 2][r] = vb.z; Bs[kk + 3][r] = vb.w;
            __syncthreads();
#pragma unroll
            for (int k = 0; k < BK; k++) {
                float a[4], b[4];
                *(float4*)a = *(const float4*)&As[k][ty * 4];
                *(float4*)b = *(const float4*)&Bs[k][tx * 4];
#pragma unroll
                for (int i2 = 0; i2 < 4; i2++)
#pragma unroll
                    for (int j2 = 0; j2 < 4; j2++)
                        acc[i2][j2] += a[i2] * b[j2];
            }
            __syncthreads();
        }
#pragma unroll
        for (int i2 = 0; i2 < 4; i2++) {
            int r = ty * 4 + i2;
#pragma unroll
            for (int j2 = 0; j2 < 4; j2++) {
                int c = tx * 4 + j2;
                float d2 = sqA[r] + sqB[c] - 2.f * acc[i2][j2];
                if (tgA[r] == tgB[c]) d2 = INFINITY;
                Cs[r][c] = d2;
            }
        }
        __syncthreads();
        if (tid < BM) {
            int r = tid;
            for (int c = 0; c < BN; c++) {
                float v = Cs[r][c];
                if (v < lv[TOPK - 1]) {
                    float nv = v; int ni = colBase + c;
#pragma unroll
                    for (int p = 0; p < TOPK; p++) {
                        if (nv < lv[p]) {
                            float tv = lv[p]; int ti = li[p];
                            lv[p] = nv; li[p] = ni;
                            nv = tv; ni = ti;
                        }
                    }
                }
            }
        }
    }
    if (tid < BM) {
        int r = tid;
#pragma unroll
        for (int k = 0; k < TOPK; k++) {
            size_t o = ((size_t)(rowBase + r) * SLICES + slice) * TOPK + k;
            part_v[o] = lv[k];
            part_i[o] = li[k];
        }
    }
}

__global__ void topk_merge_kernel(const float* __restrict__ part_v, const int* __restrict__ part_i,
                                  float* __restrict__ top_v, int* __restrict__ top_i) {
    int row = blockIdx.x * blockDim.x + threadIdx.x;
    if (row >= NROWS) return;
    float lv[TOPK]; int li[TOPK];
#pragma unroll
    for (int k = 0; k < TOPK; k++) { lv[k] = INFINITY; li[k] = -1; }
    for (int s = 0; s < SLICES; s++) {
        for (int k = 0; k < TOPK; k++) {
            size_t o = ((size_t)row * SLICES + s) * TOPK + k;
            float v = part_v[o];
            if (!(v < lv[TOPK - 1])) break;
            int idx = part_i[o];
            float nv = v; int ni = idx;
#pragma unroll
            for (int p = 0; p < TOPK; p++) {
                if (nv < lv[p]) {
                    float tv = lv[p]; int ti = li[p];
                    lv[p] = nv; li[p] = ni;
                    nv = tv; ni = ti;
                }
            }
        }
    }
#pragma unroll
    for (int k = 0; k < TOPK; k++) {
        top_v[(size_t)row * TOPK + k] = lv[k];
        top_i[(size_t)row * TOPK + k] = li[k];
    }
}

// ---------- kernel 5: per-row triplet logic (one wave per row) ----------
__global__ void rowlogic_kernel(const float* __restrict__ X, const float* __restrict__ sq,
                                const float* __restrict__ prob, const float* __restrict__ thr_p,
                                const int* __restrict__ tgt, const int* __restrict__ pred_cls,
                                const int* __restrict__ class_cnt, const int* __restrict__ class_mem,
                                const float* __restrict__ top_v, const int* __restrict__ top_i,
                                float* __restrict__ row_loss, int* __restrict__ row_corr) {
    int i = (blockIdx.x * blockDim.x + threadIdx.x) >> 6;
    int lane = threadIdx.x & 63;
    if (i >= NROWS) return;
    float thr = *thr_p;

    int c = tgt[i];
    int cc = class_cnt[c];
    const int* mem = class_mem + c * MAXM;

    int pos_i = 0;
    for (int k = 0; k < cc; k++) { if (mem[k] == i) { pos_i = k; break; } }

    int rp = 0;
    if (cc > 1) {
        uint32_t r = rnd_u32((uint32_t)i, 0x9111u) % (uint32_t)(cc - 1);
        if ((int)r >= pos_i) r++;
        rp = mem[r];
    }

    int hn = top_i[(size_t)i * TOPK + 0];
    float an0 = sqrtf(fmaxf(top_v[(size_t)i * TOPK + 0], 1e-12f));
    bool p_neg = prob[hn] >= thr;
    bool is_FN = (pred_cls[hn] == c);

    int sel = 11;
    for (int k = 1; k <= 11; k++) {
        int cd = top_i[(size_t)i * TOPK + k];
        if (prob[cd] >= thr) { sel = k; break; }
    }
    float anB = sqrtf(fmaxf(top_v[(size_t)i * TOPK + sel], 1e-12f));

    int first_valid = -1, last_draw = 0;
    for (int k = 0; k < 6; k++) {
        uint32_t r = rnd_u32((uint32_t)i, 0xD000u + (uint32_t)k) % (uint32_t)(cc > 0 ? cc : 1);
        int dk = mem[r];
        last_draw = dk;
        if (first_valid < 0 && dk != i && prob[dk] >= thr) first_valid = dk;
    }
    int rp_new = (first_valid >= 0) ? first_valid : last_draw;
    bool p_pos = prob[rp] >= thr;

    const float4* xi = (const float4*)(X + (size_t)i * DIM);
    const float4* xr = (const float4*)(X + (size_t)rp * DIM);
    const float4* xn = (const float4*)(X + (size_t)rp_new * DIM);
    float s1 = 0.f, s2 = 0.f;
    for (int k = lane; k < DIM / 4; k += 64) {
        float4 a = xi[k], b = xr[k], d = xn[k];
        s1 += a.x * b.x + a.y * b.y + a.z * b.z + a.w * b.w;
        s2 += a.x * d.x + a.y * d.y + a.z * d.z + a.w * d.w;
    }
    for (int off = 32; off; off >>= 1) {
        s1 += __shfl_xor(s1, off, 64);
        s2 += __shfl_xor(s2, off, 64);
    }
    if (lane == 0) {
        float ap0 = sqrtf(fmaxf(sq[i] + sq[rp]     - 2.f * s1, 1e-12f));
        float apC = sqrtf(fmaxf(sq[i] + sq[rp_new] - 2.f * s2, 1e-12f));
        float apB = (ap0 + an0) * 0.5f;
        float anC = (ap0 + an0) * 0.5f;
        bool useB = p_pos && !p_neg && is_FN;
        bool useC = (!p_pos && p_neg) || (!p_pos && !p_neg && !is_FN);
        bool inverse = !p_pos && !p_neg && is_FN;
        float ap = useB ? apB : (useC ? apC : ap0);
        float an = useB ? anB : (useC ? anC : an0);
        float pl = inverse ? fmaxf(an - ap + MARGIN_F, 0.f)
                           : fmaxf(ap - an + MARGIN_F, 0.f);
        bool conf = prob[i] >= thr;
        row_loss[i] = conf ? pl : 0.f;
        row_corr[i] = (conf && (an >= ap)) ? 1 : 0;
    }
}

// ---------- kernel 6: final reduction ----------
__global__ void reduce_kernel(const float* __restrict__ row_loss, const int* __restrict__ row_corr,
                              const float* __restrict__ prob, const float* __restrict__ thr_p,
                              float* __restrict__ out) {
    __shared__ float sl[256];
    __shared__ int   sc[256];
    __shared__ int   sn[256];
    float thr = *thr_p;
    int tid = threadIdx.x;
    float l = 0.f; int corr = 0, cnt = 0;
    for (int i = tid; i < NROWS; i += 256) {
        l += row_loss[i];
        corr += row_corr[i];
        cnt += (prob[i] >= thr) ? 1 : 0;
    }
    sl[tid] = l; sc[tid] = corr; sn[tid] = cnt;
    __syncthreads();
    for (int off = 128; off; off >>= 1) {
        if (tid < off) {
            sl[tid] += sl[tid + off];
            sc[tid] += sc[tid + off];
            sn[tid] += sn[tid + off];
        }
        __syncthreads();
    }
    if (tid == 0) {
        int cn = sn[0];
        float loss = (cn > 0) ? (sl[0] / (float)(cn > 1 ? cn : 1)) : 0.f;
        out[0] = loss;
        out[1] = (float)sc[0];
        out[2] = (float)cn;
    }
}

extern "C" void kernel_launch(void* const* d_in, const int* in_sizes, int n_in,
                              void* d_out, int out_size, void* d_ws, size_t ws_size,
                              hipStream_t stream) {
    const float* X    = (const float*)d_in[0];
    const float* P    = (const float*)d_in[1];
    const int*   tgt  = (const int*)d_in[2];
    const float* prob = (const float*)d_in[4];
    const float* thr  = (const float*)d_in[5];
    float* out = (float*)d_out;

    char* w = (char*)d_ws;
    auto alloc = [&](size_t bytes) {
        char* p = w;
        w += (bytes + 255) & ~(size_t)255;
        return p;
    };
    float* sq        = (float*)alloc(NROWS * sizeof(float));
    int*   pred_cls  = (int*)  alloc(NROWS * sizeof(int));
    int*   class_cnt = (int*)  alloc(CNUM * sizeof(int));
    int*   class_mem = (int*)  alloc((size_t)CNUM * MAXM * sizeof(int));
    float* top_v     = (float*)alloc((size_t)NROWS * TOPK * sizeof(float));
    int*   top_i     = (int*)  alloc((size_t)NROWS * TOPK * sizeof(int));
    float* row_loss  = (float*)alloc(NROWS * sizeof(float));
    int*   row_corr  = (int*)  alloc(NROWS * sizeof(int));
    char*  var_base  = w;

    size_t fast_need = (size_t)NROWS * DIM * 2 + (size_t)NROWS * NROWS * 4 + (1 << 20);
    bool fast = ((size_t)(var_base - (char*)d_ws) + fast_need) <= ws_size;

    predcls_kernel<<<NROWS / 4, 256, 0, stream>>>(P, pred_cls);
    classlist_kernel<<<CNUM / 4, 256, 0, stream>>>(tgt, class_cnt, class_mem);

    if (fast) {
        _Float16* Xh   = (_Float16*)alloc((size_t)NROWS * DIM * 2);
        float*    dist = (float*)alloc((size_t)NROWS * NROWS * 4);
        prep_kernel<<<NROWS, 256, 0, stream>>>(X, Xh, sq);
        mfma_dist_kernel<<<528, 256, 0, stream>>>(Xh, sq, tgt, dist);
        topk_kernel<<<NROWS / 4, 256, 0, stream>>>(dist, top_v, top_i);
    } else {
        rowsq_kernel<<<NROWS / 4, 256, 0, stream>>>(X, sq);
        float* part_v = (float*)alloc((size_t)NROWS * SLICES * TOPK * sizeof(float));
        int*   part_i = (int*)  alloc((size_t)NROWS * SLICES * TOPK * sizeof(int));
        dist_topk_kernel<<<dim3(NROWS / BM, SLICES), 256, 0, stream>>>(X, sq, tgt, part_v, part_i);
        topk_merge_kernel<<<NROWS / 256, 256, 0, stream>>>(part_v, part_i, top_v, top_i);
    }

    rowlogic_kernel<<<NROWS / 4, 256, 0, stream>>>(X, sq, prob, thr, tgt, pred_cls,
                                                   class_cnt, class_mem, top_v, top_i,
                                                   row_loss, row_corr);
    reduce_kernel<<<1, 256, 0, stream>>>(row_loss, row_corr, prob, thr, out);
}

// Round 7
// 227.033 us; speedup vs baseline: 8.4416x; 1.0385x over previous
//
#include <hip/hip_runtime.h>
#include <hip/hip_bf16.h>
#include <cstdint>
#include <cmath>

#define NROWS 4096
#define DIM   2048
#define CNUM  128
#define MARGIN_F 0.3f
#define TOPK 12
#define MAXM 256
#define GBK 32          // K-tile (f16 elements), double-buffered
#define CAP 160         // topk candidate buffer per wave

// fallback-path tiling
#define BM 64
#define BN 64
#define BK 16
#define SLICES 8
#define COLS_PER_SLICE (NROWS / SLICES)

typedef _Float16 f16x8 __attribute__((ext_vector_type(8)));
typedef float    f32x4 __attribute__((ext_vector_type(4)));

// async global->LDS, 16 B per lane; lds dest = wave-uniform base + lane*16
#define GLD_LDS16(g, l)                                                        \
    __builtin_amdgcn_global_load_lds(                                          \
        (const __attribute__((address_space(1))) uint32_t*)(g),                \
        (__attribute__((address_space(3))) uint32_t*)(l), 16, 0, 0)

__device__ __forceinline__ uint32_t rnd_u32(uint32_t row, uint32_t k) {
    uint64_t x = ((uint64_t)row << 32) ^ (0x9E3779B97F4A7C15ULL * (uint64_t)(k + 1u));
    x ^= x >> 33; x *= 0xff51afd7ed558ccdULL;
    x ^= x >> 33; x *= 0xc4ceb9fe1a85ec53ULL;
    x ^= x >> 33;
    return (uint32_t)x;
}

// ---------- kernel 1a: row sum of squares (fallback path) ----------
__global__ void rowsq_kernel(const float* __restrict__ X, float* __restrict__ sq) {
    int wave = (blockIdx.x * blockDim.x + threadIdx.x) >> 6;
    int lane = threadIdx.x & 63;
    if (wave >= NROWS) return;
    const float4* xp = (const float4*)(X + (size_t)wave * DIM);
    float s = 0.f;
    for (int k = lane; k < DIM / 4; k += 64) {
        float4 v = xp[k];
        s += v.x * v.x + v.y * v.y + v.z * v.z + v.w * v.w;
    }
    for (int off = 32; off; off >>= 1) s += __shfl_xor(s, off, 64);
    if (lane == 0) sq[wave] = s;
}

// ---------- fast path: fused fp32->f16 convert + row sum of squares ----------
__global__ void prep_kernel(const float* __restrict__ X, _Float16* __restrict__ Xh,
                            float* __restrict__ sq) {
    __shared__ float ws[4];
    int row = blockIdx.x, tid = threadIdx.x;
    int wave = tid >> 6, lane = tid & 63;
    const float4* xp = (const float4*)(X + (size_t)row * DIM);
    float4 a = xp[tid * 2], b = xp[tid * 2 + 1];
    float s = a.x * a.x + a.y * a.y + a.z * a.z + a.w * a.w
            + b.x * b.x + b.y * b.y + b.z * b.z + b.w * b.w;
    _Float16 h[8] = { (_Float16)a.x, (_Float16)a.y, (_Float16)a.z, (_Float16)a.w,
                      (_Float16)b.x, (_Float16)b.y, (_Float16)b.z, (_Float16)b.w };
    ((uint4*)(Xh + (size_t)row * DIM))[tid] = *(uint4*)h;
    for (int off = 32; off; off >>= 1) s += __shfl_xor(s, off, 64);
    if (lane == 0) ws[wave] = s;
    __syncthreads();
    if (tid == 0) sq[row] = ws[0] + ws[1] + ws[2] + ws[3];
}

// ---------- kernel 1b: pred_cls = argmax over C=128 (one wave per row) ----------
__global__ void predcls_kernel(const float* __restrict__ P, int* __restrict__ cls) {
    int row = (blockIdx.x * blockDim.x + threadIdx.x) >> 6;
    int lane = threadIdx.x & 63;
    if (row >= NROWS) return;
    const float* p = P + (size_t)row * CNUM;
    float v0 = p[lane]; int i0 = lane;
    float v1 = p[lane + 64];
    if (v1 > v0) { v0 = v1; i0 = lane + 64; }
    for (int off = 1; off < 64; off <<= 1) {
        float ov = __shfl_xor(v0, off, 64);
        int   oi = __shfl_xor(i0, off, 64);
        if (ov > v0 || (ov == v0 && oi < i0)) { v0 = ov; i0 = oi; }
    }
    if (lane == 0) cls[row] = i0;
}

// ---------- kernel 2: per-class member lists via wave ballot compaction ----------
__global__ void classlist_kernel(const int* __restrict__ tgt,
                                 int* __restrict__ cnt, int* __restrict__ members) {
    int c = (blockIdx.x * blockDim.x + threadIdx.x) >> 6;
    int lane = threadIdx.x & 63;
    if (c >= CNUM) return;
    int k = 0;
    for (int base = 0; base < NROWS; base += 64) {
        int i = base + lane;
        bool m = (tgt[i] == c);
        unsigned long long mask = __ballot(m);
        if (m) {
            int pos = k + __popcll(mask & ((1ull << lane) - 1ull));
            if (pos < MAXM) members[c * MAXM + pos] = i;
        }
        k += __popcll(mask);
    }
    if (lane == 0) cnt[c] = (k < MAXM) ? k : MAXM;
}

// ---------- fast path: f16 MFMA Gram, BK=32 double-buffered, all-resident grid ----
// 528 upper-triangle 128x128 tiles; LDS = 2x8KB A + 2x8KB B + ~7KB epilogue ≈ 39KB
// -> 4 blocks/CU capacity -> ALL 528 blocks co-resident (no serial tail), and
// 3-4 waves/SIMD hide the per-iteration staging latency.
// Swizzle: row r's 16B chunk c stored at slot (c + (r>>1)) & 3  -> 2-way banks (free).
__launch_bounds__(256, 4)
__global__ void mfma_dist_kernel(const _Float16* __restrict__ Xh,
                                 const float* __restrict__ sq, const int* __restrict__ tgt,
                                 float* __restrict__ dist) {
    __shared__ _Float16 Ah[2][128 * GBK];   // 2 x 8 KB
    __shared__ _Float16 Bh[2][128 * GBK];   // 2 x 8 KB
    __shared__ float    trb[4][16 * 17];
    __shared__ float    sqA[128], sqB[128];
    __shared__ int      tgA[128], tgB[128];

    int b = blockIdx.x;
    int br = 0, S = 0;
    while (b >= S + (32 - br)) { S += 32 - br; br++; }
    int bc = br + (b - S);

    int r0 = br * 128, c0 = bc * 128;
    int tid = threadIdx.x;
    int wave = tid >> 6, lane = tid & 63;
    int wr = wave >> 1, wc = wave & 1;

    if (tid < 128) { sqA[tid] = sq[r0 + tid]; tgA[tid] = tgt[r0 + tid]; }
    else { int t = tid - 128; sqB[t] = sq[c0 + t]; tgB[t] = tgt[c0 + t]; }

    f32x4 acc[4][4];
#pragma unroll
    for (int i = 0; i < 4; i++)
#pragma unroll
        for (int j = 0; j < 4; j++) acc[i][j] = (f32x4)0.f;

    // staging: wave w loads A rows [w*32, w*32+32) and B rows likewise,
    // as 2 issues x 16 rows (1 KB each issue).
    const _Float16* gA[2]; const _Float16* gB[2];
    int ldsOff[2];
#pragma unroll
    for (int q = 0; q < 2; q++) {
        int rl = wave * 32 + q * 16 + (lane >> 2);        // local row 0..127
        int slot = lane & 3;                              // dest 16B slot in row
        int c = (slot - ((rl >> 1) & 3)) & 3;             // source chunk for this slot
        gA[q] = Xh + (size_t)(r0 + rl) * DIM + c * 8;
        gB[q] = Xh + (size_t)(c0 + rl) * DIM + c * 8;
        ldsOff[q] = (wave * 32 + q * 16) * GBK;           // wave-uniform base
    }

    auto stage = [&](int buf, int kOff) {
#pragma unroll
        for (int q = 0; q < 2; q++) {
            GLD_LDS16(gA[q] + kOff, &Ah[buf][ldsOff[q]]);
            GLD_LDS16(gB[q] + kOff, &Bh[buf][ldsOff[q]]);
        }
    };

    stage(0, 0);
    int fr = lane & 15, fq = lane >> 4;

    for (int it = 0; it < DIM / GBK; it++) {              // 64 iterations
        int cur = it & 1;
        __syncthreads();                                  // prefetch drained; buffer safe
        if (it + 1 < DIM / GBK) stage(cur ^ 1, (it + 1) * GBK);
        f16x8 af[4], bf[4];
#pragma unroll
        for (int i = 0; i < 4; i++) {
            int row = wr * 64 + i * 16 + fr;
            int slot = (fq + ((row >> 1) & 3)) & 3;
            af[i] = *(const f16x8*)&Ah[cur][row * GBK + slot * 8];
        }
#pragma unroll
        for (int j = 0; j < 4; j++) {
            int col = wc * 64 + j * 16 + fr;
            int slot = (fq + ((col >> 1) & 3)) & 3;
            bf[j] = *(const f16x8*)&Bh[cur][col * GBK + slot * 8];
        }
#pragma unroll
        for (int i = 0; i < 4; i++)
#pragma unroll
            for (int j = 0; j < 4; j++)
                acc[i][j] = __builtin_amdgcn_mfma_f32_16x16x32_f16(af[i], bf[j], acc[i][j], 0, 0, 0);
    }

    // epilogue: d2 = sqA+sqB-2*dot, mask positives; direct + LDS-transposed mirror
    float* tb = trb[wave];
#pragma unroll
    for (int i = 0; i < 4; i++) {
#pragma unroll
        for (int j = 0; j < 4; j++) {
            int lcol = wc * 64 + j * 16 + fr;
            float d[4];
#pragma unroll
            for (int r = 0; r < 4; r++) {
                int lrow = wr * 64 + i * 16 + fq * 4 + r;
                float v = sqA[lrow] + sqB[lcol] - 2.f * acc[i][j][r];
                if (tgA[lrow] == tgB[lcol]) v = INFINITY;
                d[r] = v;
                dist[(size_t)(r0 + lrow) * NROWS + (c0 + lcol)] = v;
            }
            if (br != bc) {
#pragma unroll
                for (int r = 0; r < 4; r++) tb[fr * 17 + fq * 4 + r] = d[r];
#pragma unroll
                for (int r = 0; r < 4; r++) {
                    float v = tb[(fq * 4 + r) * 17 + fr];
                    int grow = c0 + wc * 64 + j * 16 + fq * 4 + r;
                    int gcol = r0 + wr * 64 + i * 16 + fr;
                    dist[(size_t)grow * NROWS + gcol] = v;
                }
            }
        }
    }
}

// ---------- fast path: per-row top-12 via pivot filter + ballot compaction ----------
__launch_bounds__(256)
__global__ void topk_kernel(const float* __restrict__ dist,
                            float* __restrict__ top_v, int* __restrict__ top_i) {
    __shared__ float cbv[4][CAP];
    __shared__ int   cbi[4][CAP];
    int wave = threadIdx.x >> 6, lane = threadIdx.x & 63;
    int row = blockIdx.x * 4 + wave;
    const float4* d = (const float4*)(dist + (size_t)row * NROWS);

    float4 v[16];
#pragma unroll
    for (int t = 0; t < 16; t++) v[t] = d[t * 64 + lane];

    float lmin = INFINITY, lmax = -INFINITY, lsum = 0.f;
    int lcnt = 0;
#pragma unroll
    for (int t = 0; t < 16; t++) {
        float xs[4] = { v[t].x, v[t].y, v[t].z, v[t].w };
#pragma unroll
        for (int c = 0; c < 4; c++) {
            float x = xs[c];
            bool fin = x < INFINITY;
            lmin = fminf(lmin, x);
            lmax = fmaxf(lmax, fin ? x : -INFINITY);
            lsum += fin ? x : 0.f;
            lcnt += fin ? 1 : 0;
        }
    }
    for (int off = 32; off; off >>= 1) {
        lmin = fminf(lmin, __shfl_xor(lmin, off, 64));
        lmax = fmaxf(lmax, __shfl_xor(lmax, off, 64));
        lsum += __shfl_xor(lsum, off, 64);
        lcnt += __shfl_xor(lcnt, off, 64);
    }
    float mu = lsum / (float)(lcnt > 0 ? lcnt : 1);

    float lo = lmin, hi = lmax + 1.0f;
    float tau = lmin + 0.3f * (mu - lmin);
    if (!(tau > lo && tau < hi)) tau = 0.5f * (lo + hi);
    for (int it = 0; it < 32; it++) {
        int lc = 0;
#pragma unroll
        for (int t = 0; t < 16; t++) {
            lc += (v[t].x < tau) + (v[t].y < tau) + (v[t].z < tau) + (v[t].w < tau);
        }
        for (int off = 32; off; off >>= 1) lc += __shfl_xor(lc, off, 64);
        if (lc >= TOPK && lc <= CAP) break;
        if (lc < TOPK) lo = tau; else hi = tau;
        tau = 0.5f * (lo + hi);
    }

    int cnt = 0;
#pragma unroll
    for (int t = 0; t < 16; t++) {
        float xs[4] = { v[t].x, v[t].y, v[t].z, v[t].w };
#pragma unroll
        for (int c = 0; c < 4; c++) {
            float x = xs[c];
            bool p = x < tau;
            unsigned long long mk = __ballot(p);
            if (p) {
                int pos = cnt + __popcll(mk & ((1ull << lane) - 1ull));
                if (pos < CAP) {
                    cbv[wave][pos] = x;
                    cbi[wave][pos] = (t * 64 + lane) * 4 + c;
                }
            }
            cnt += __popcll(mk);
        }
    }
    if (cnt > CAP) cnt = CAP;

    float mv[3]; int mi[3];
#pragma unroll
    for (int r = 0; r < 3; r++) {
        int p = r * 64 + lane;
        bool ok = p < cnt;
        mv[r] = ok ? cbv[wave][p] : INFINITY;
        mi[r] = ok ? cbi[wave][p] : 0x7FFFFFFF;
    }

    for (int t = 0; t < TOPK; t++) {
        float bv = mv[0]; int bi = mi[0];
        if (mv[1] < bv || (mv[1] == bv && mi[1] < bi)) { bv = mv[1]; bi = mi[1]; }
        if (mv[2] < bv || (mv[2] == bv && mi[2] < bi)) { bv = mv[2]; bi = mi[2]; }
        for (int off = 32; off; off >>= 1) {
            float ov = __shfl_xor(bv, off, 64);
            int   oi = __shfl_xor(bi, off, 64);
            if (ov < bv || (ov == bv && oi < bi)) { bv = ov; bi = oi; }
        }
        if (lane == 0) {
            top_v[(size_t)row * TOPK + t] = bv;
            int si = (bi >= 0 && bi < NROWS) ? bi : 0;
            top_i[(size_t)row * TOPK + t] = si;
        }
#pragma unroll
        for (int r = 0; r < 3; r++)
            if (mi[r] == bi) { mv[r] = INFINITY; mi[r] = 0x7FFFFFFF; }
    }
}

// ---------- fallback path (proven R1): fused fp32 GEMM + per-row top-12 ----------
__launch_bounds__(256)
__global__ void dist_topk_kernel(const float* __restrict__ X, const float* __restrict__ sq,
                                 const int* __restrict__ tgt,
                                 float* __restrict__ part_v, int* __restrict__ part_i) {
    __shared__ float As[BK][BM];
    __shared__ float Bs[BK][BN];
    __shared__ float Cs[BM][BN + 1];
    __shared__ float sqA[BM], sqB[BN];
    __shared__ int   tgA[BM], tgB[BN];

    int rowBase = blockIdx.x * BM;
    int slice = blockIdx.y;
    int tid = threadIdx.x;
    int tx = tid & 15, ty = tid >> 4;

    if (tid < BM) { sqA[tid] = sq[rowBase + tid]; tgA[tid] = tgt[rowBase + tid]; }

    float lv[TOPK]; int li[TOPK];
#pragma unroll
    for (int k = 0; k < TOPK; k++) { lv[k] = INFINITY; li[k] = -1; }

    for (int jt = 0; jt < COLS_PER_SLICE / BN; jt++) {
        int colBase = slice * COLS_PER_SLICE + jt * BN;
        __syncthreads();
        if (tid < BN) { sqB[tid] = sq[colBase + tid]; tgB[tid] = tgt[colBase + tid]; }

        float acc[4][4] = {};
        for (int kb = 0; kb < DIM; kb += BK) {
            int r  = tid >> 2;
            int kk = (tid & 3) * 4;
            float4 va = *(const float4*)(X + (size_t)(rowBase + r) * DIM + kb + kk);
            As[kk + 0][r] = va.x; As[kk + 1][r] = va.y; As[kk + 2][r] = va.z; As[kk + 3][r] = va.w;
            float4 vb = *(const float4*)(X + (size_t)(colBase + r) * DIM + kb + kk);
            Bs[kk + 0][r] = vb.x; Bs[kk + 1][r] = vb.y; Bs[kk + 2][r] = vb.z; Bs[kk + 3][r] = vb.w;
            __syncthreads();
#pragma unroll
            for (int k = 0; k < BK; k++) {
                float a[4], b2[4];
                *(float4*)a = *(const float4*)&As[k][ty * 4];
                *(float4*)b2 = *(const float4*)&Bs[k][tx * 4];
#pragma unroll
                for (int i2 = 0; i2 < 4; i2++)
#pragma unroll
                    for (int j2 = 0; j2 < 4; j2++)
                        acc[i2][j2] += a[i2] * b2[j2];
            }
            __syncthreads();
        }
#pragma unroll
        for (int i2 = 0; i2 < 4; i2++) {
            int r = ty * 4 + i2;
#pragma unroll
            for (int j2 = 0; j2 < 4; j2++) {
                int c = tx * 4 + j2;
                float d2 = sqA[r] + sqB[c] - 2.f * acc[i2][j2];
                if (tgA[r] == tgB[c]) d2 = INFINITY;
                Cs[r][c] = d2;
            }
        }
        __syncthreads();
        if (tid < BM) {
            int r = tid;
            for (int c = 0; c < BN; c++) {
                float v = Cs[r][c];
                if (v < lv[TOPK - 1]) {
                    float nv = v; int ni = colBase + c;
#pragma unroll
                    for (int p = 0; p < TOPK; p++) {
                        if (nv < lv[p]) {
                            float tv = lv[p]; int ti = li[p];
                            lv[p] = nv; li[p] = ni;
                            nv = tv; ni = ti;
                        }
                    }
                }
            }
        }
    }
    if (tid < BM) {
        int r = tid;
#pragma unroll
        for (int k = 0; k < TOPK; k++) {
            size_t o = ((size_t)(rowBase + r) * SLICES + slice) * TOPK + k;
            part_v[o] = lv[k];
            part_i[o] = li[k];
        }
    }
}

__global__ void topk_merge_kernel(const float* __restrict__ part_v, const int* __restrict__ part_i,
                                  float* __restrict__ top_v, int* __restrict__ top_i) {
    int row = blockIdx.x * blockDim.x + threadIdx.x;
    if (row >= NROWS) return;
    float lv[TOPK]; int li[TOPK];
#pragma unroll
    for (int k = 0; k < TOPK; k++) { lv[k] = INFINITY; li[k] = -1; }
    for (int s = 0; s < SLICES; s++) {
        for (int k = 0; k < TOPK; k++) {
            size_t o = ((size_t)row * SLICES + s) * TOPK + k;
            float v = part_v[o];
            if (!(v < lv[TOPK - 1])) break;
            int idx = part_i[o];
            float nv = v; int ni = idx;
#pragma unroll
            for (int p = 0; p < TOPK; p++) {
                if (nv < lv[p]) {
                    float tv = lv[p]; int ti = li[p];
                    lv[p] = nv; li[p] = ni;
                    nv = tv; ni = ti;
                }
            }
        }
    }
#pragma unroll
    for (int k = 0; k < TOPK; k++) {
        top_v[(size_t)row * TOPK + k] = lv[k];
        top_i[(size_t)row * TOPK + k] = li[k];
    }
}

// ---------- kernel 5: per-row triplet logic (one wave per row) ----------
__global__ void rowlogic_kernel(const float* __restrict__ X, const float* __restrict__ sq,
                                const float* __restrict__ prob, const float* __restrict__ thr_p,
                                const int* __restrict__ tgt, const int* __restrict__ pred_cls,
                                const int* __restrict__ class_cnt, const int* __restrict__ class_mem,
                                const float* __restrict__ top_v, const int* __restrict__ top_i,
                                float* __restrict__ row_loss, int* __restrict__ row_corr) {
    int i = (blockIdx.x * blockDim.x + threadIdx.x) >> 6;
    int lane = threadIdx.x & 63;
    if (i >= NROWS) return;
    float thr = *thr_p;

    int c = tgt[i];
    int cc = class_cnt[c];
    const int* mem = class_mem + c * MAXM;

    int pos_i = 0;
    for (int k = 0; k < cc; k++) { if (mem[k] == i) { pos_i = k; break; } }

    int rp = 0;
    if (cc > 1) {
        uint32_t r = rnd_u32((uint32_t)i, 0x9111u) % (uint32_t)(cc - 1);
        if ((int)r >= pos_i) r++;
        rp = mem[r];
    }

    int hn = top_i[(size_t)i * TOPK + 0];
    float an0 = sqrtf(fmaxf(top_v[(size_t)i * TOPK + 0], 1e-12f));
    bool p_neg = prob[hn] >= thr;
    bool is_FN = (pred_cls[hn] == c);

    int sel = 11;
    for (int k = 1; k <= 11; k++) {
        int cd = top_i[(size_t)i * TOPK + k];
        if (prob[cd] >= thr) { sel = k; break; }
    }
    float anB = sqrtf(fmaxf(top_v[(size_t)i * TOPK + sel], 1e-12f));

    int first_valid = -1, last_draw = 0;
    for (int k = 0; k < 6; k++) {
        uint32_t r = rnd_u32((uint32_t)i, 0xD000u + (uint32_t)k) % (uint32_t)(cc > 0 ? cc : 1);
        int dk = mem[r];
        last_draw = dk;
        if (first_valid < 0 && dk != i && prob[dk] >= thr) first_valid = dk;
    }
    int rp_new = (first_valid >= 0) ? first_valid : last_draw;
    bool p_pos = prob[rp] >= thr;

    const float4* xi = (const float4*)(X + (size_t)i * DIM);
    const float4* xr = (const float4*)(X + (size_t)rp * DIM);
    const float4* xn = (const float4*)(X + (size_t)rp_new * DIM);
    float s1 = 0.f, s2 = 0.f;
    for (int k = lane; k < DIM / 4; k += 64) {
        float4 a = xi[k], b = xr[k], d = xn[k];
        s1 += a.x * b.x + a.y * b.y + a.z * b.z + a.w * b.w;
        s2 += a.x * d.x + a.y * d.y + a.z * d.z + a.w * d.w;
    }
    for (int off = 32; off; off >>= 1) {
        s1 += __shfl_xor(s1, off, 64);
        s2 += __shfl_xor(s2, off, 64);
    }
    if (lane == 0) {
        float ap0 = sqrtf(fmaxf(sq[i] + sq[rp]     - 2.f * s1, 1e-12f));
        float apC = sqrtf(fmaxf(sq[i] + sq[rp_new] - 2.f * s2, 1e-12f));
        float apB = (ap0 + an0) * 0.5f;
        float anC = (ap0 + an0) * 0.5f;
        bool useB = p_pos && !p_neg && is_FN;
        bool useC = (!p_pos && p_neg) || (!p_pos && !p_neg && !is_FN);
        bool inverse = !p_pos && !p_neg && is_FN;
        float ap = useB ? apB : (useC ? apC : ap0);
        float an = useB ? anB : (useC ? anC : an0);
        float pl = inverse ? fmaxf(an - ap + MARGIN_F, 0.f)
                           : fmaxf(ap - an + MARGIN_F, 0.f);
        bool conf = prob[i] >= thr;
        row_loss[i] = conf ? pl : 0.f;
        row_corr[i] = (conf && (an >= ap)) ? 1 : 0;
    }
}

// ---------- kernel 6: final reduction ----------
__global__ void reduce_kernel(const float* __restrict__ row_loss, const int* __restrict__ row_corr,
                              const float* __restrict__ prob, const float* __restrict__ thr_p,
                              float* __restrict__ out) {
    __shared__ float sl[256];
    __shared__ int   sc[256];
    __shared__ int   sn[256];
    float thr = *thr_p;
    int tid = threadIdx.x;
    float l = 0.f; int corr = 0, cnt = 0;
    for (int i = tid; i < NROWS; i += 256) {
        l += row_loss[i];
        corr += row_corr[i];
        cnt += (prob[i] >= thr) ? 1 : 0;
    }
    sl[tid] = l; sc[tid] = corr; sn[tid] = cnt;
    __syncthreads();
    for (int off = 128; off; off >>= 1) {
        if (tid < off) {
            sl[tid] += sl[tid + off];
            sc[tid] += sc[tid + off];
            sn[tid] += sn[tid + off];
        }
        __syncthreads();
    }
    if (tid == 0) {
        int cn = sn[0];
        float loss = (cn > 0) ? (sl[0] / (float)(cn > 1 ? cn : 1)) : 0.f;
        out[0] = loss;
        out[1] = (float)sc[0];
        out[2] = (float)cn;
    }
}

extern "C" void kernel_launch(void* const* d_in, const int* in_sizes, int n_in,
                              void* d_out, int out_size, void* d_ws, size_t ws_size,
                              hipStream_t stream) {
    const float* X    = (const float*)d_in[0];
    const float* P    = (const float*)d_in[1];
    const int*   tgt  = (const int*)d_in[2];
    const float* prob = (const float*)d_in[4];
    const float* thr  = (const float*)d_in[5];
    float* out = (float*)d_out;

    char* w = (char*)d_ws;
    auto alloc = [&](size_t bytes) {
        char* p = w;
        w += (bytes + 255) & ~(size_t)255;
        return p;
    };
    float* sq        = (float*)alloc(NROWS * sizeof(float));
    int*   pred_cls  = (int*)  alloc(NROWS * sizeof(int));
    int*   class_cnt = (int*)  alloc(CNUM * sizeof(int));
    int*   class_mem = (int*)  alloc((size_t)CNUM * MAXM * sizeof(int));
    float* top_v     = (float*)alloc((size_t)NROWS * TOPK * sizeof(float));
    int*   top_i     = (int*)  alloc((size_t)NROWS * TOPK * sizeof(int));
    float* row_loss  = (float*)alloc(NROWS * sizeof(float));
    int*   row_corr  = (int*)  alloc(NROWS * sizeof(int));
    char*  var_base  = w;

    size_t fast_need = (size_t)NROWS * DIM * 2 + (size_t)NROWS * NROWS * 4 + (1 << 20);
    bool fast = ((size_t)(var_base - (char*)d_ws) + fast_need) <= ws_size;

    predcls_kernel<<<NROWS / 4, 256, 0, stream>>>(P, pred_cls);
    classlist_kernel<<<CNUM / 4, 256, 0, stream>>>(tgt, class_cnt, class_mem);

    if (fast) {
        _Float16* Xh   = (_Float16*)alloc((size_t)NROWS * DIM * 2);
        float*    dist = (float*)alloc((size_t)NROWS * NROWS * 4);
        prep_kernel<<<NROWS, 256, 0, stream>>>(X, Xh, sq);
        mfma_dist_kernel<<<528, 256, 0, stream>>>(Xh, sq, tgt, dist);
        topk_kernel<<<NROWS / 4, 256, 0, stream>>>(dist, top_v, top_i);
    } else {
        rowsq_kernel<<<NROWS / 4, 256, 0, stream>>>(X, sq);
        float* part_v = (float*)alloc((size_t)NROWS * SLICES * TOPK * sizeof(float));
        int*   part_i = (int*)  alloc((size_t)NROWS * SLICES * TOPK * sizeof(int));
        dist_topk_kernel<<<dim3(NROWS / BM, SLICES), 256, 0, stream>>>(X, sq, tgt, part_v, part_i);
        topk_merge_kernel<<<NROWS / 256, 256, 0, stream>>>(part_v, part_i, top_v, top_i);
    }

    rowlogic_kernel<<<NROWS / 4, 256, 0, stream>>>(X, sq, prob, thr, tgt, pred_cls,
                                                   class_cnt, class_mem, top_v, top_i,
                                                   row_loss, row_corr);
    reduce_kernel<<<1, 256, 0, stream>>>(row_loss, row_corr, prob, thr, out);
}